// Round 6
// baseline (626.451 us; speedup 1.0000x reference)
//
#include <hip/hip_runtime.h>

typedef unsigned short u16;
typedef unsigned int u32;
typedef unsigned long long u64;

#define T_TOK 8192
#define DIM 768
#define FF 3072
#define NE 8
#define CAP 2560
#define LSTR 5120
#define NCAST 27648  // 3 * (NE*FF*DIM/8) / 256 cast blocks

typedef __attribute__((ext_vector_type(8))) short s8v;
typedef __attribute__((ext_vector_type(4))) float f4v;

__device__ __forceinline__ u16 f2bf(float f) {
  union { float f; u32 u; } v; v.f = f;
  u32 r = v.u + 0x7FFFu + ((v.u >> 16) & 1u);
  return (u16)(r >> 16);
}

__device__ __forceinline__ void glds16(const void* g, void* l) {
  __builtin_amdgcn_global_load_lds(
      (const __attribute__((address_space(1))) u32*)g,
      (__attribute__((address_space(3))) u32*)l, 16, 0, 0);
}

// raw barrier: convergent builtin + compiler memory fence; does NOT drain counters
#define BARRIER() do { asm volatile("" ::: "memory"); __builtin_amdgcn_s_barrier(); asm volatile("" ::: "memory"); } while (0)
#define WAITV(N) asm volatile("s_waitcnt vmcnt(" #N ")" ::: "memory")
#define WAITL() asm volatile("s_waitcnt lgkmcnt(0)" ::: "memory")
#define PRIO1 __builtin_amdgcn_s_setprio(1)
#define PRIO0 __builtin_amdgcn_s_setprio(0)

// ---------------- fused: weight casts (blocks 0..NCAST-1) + router (rest) ----------------
__global__ __launch_bounds__(256) void pre_kernel(
    const float* __restrict__ wig, const float* __restrict__ wiu, const float* __restrict__ wo,
    u16* __restrict__ wgb, u16* __restrict__ wub, u16* __restrict__ wob, int n8each,
    const float* __restrict__ x, const float* __restrict__ wg, u16* __restrict__ xb,
    int* __restrict__ tki, float* __restrict__ tkp,
    float* __restrict__ probs, float* __restrict__ lse2) {
  int bid = blockIdx.x;
  if (bid < NCAST) {
    // ---- cast part ----
    int i = bid * 256 + threadIdx.x;
    const float* s; u16* d; int j;
    if (i < n8each) { s = wig; d = wgb; j = i; }
    else if (i < 2 * n8each) { s = wiu; d = wub; j = i - n8each; }
    else { s = wo; d = wob; j = i - 2 * n8each; }
    const float4* s4 = (const float4*)s;
    float4 a = s4[2 * j], b = s4[2 * j + 1];
    uint4 o;
    o.x = (u32)f2bf(a.x) | ((u32)f2bf(a.y) << 16);
    o.y = (u32)f2bf(a.z) | ((u32)f2bf(a.w) << 16);
    o.z = (u32)f2bf(b.x) | ((u32)f2bf(b.y) << 16);
    o.w = (u32)f2bf(b.z) | ((u32)f2bf(b.w) << 16);
    ((uint4*)d)[j] = o;
    return;
  }
  // ---- router part ----
  int rb = bid - NCAST;
  int lane = threadIdx.x & 63;
  int t = rb * 4 + (threadIdx.x >> 6);
  const float* xr = x + (long)t * DIM;
  u16* xw = xb + (long)t * DIM;
  float acc[NE];
#pragma unroll
  for (int e = 0; e < NE; e++) acc[e] = 0.f;
  for (int i = 0; i < DIM / 64; i++) {
    float xv = xr[lane + 64 * i];
    xw[lane + 64 * i] = f2bf(xv);
#pragma unroll
    for (int e = 0; e < NE; e++) acc[e] += xv * wg[e * DIM + lane + 64 * i];
  }
#pragma unroll
  for (int off = 32; off > 0; off >>= 1) {
#pragma unroll
    for (int e = 0; e < NE; e++) acc[e] += __shfl_xor(acc[e], off);
  }
  if (lane == 0) {
    float m = acc[0];
#pragma unroll
    for (int e = 1; e < NE; e++) m = fmaxf(m, acc[e]);
    float p[NE], s = 0.f;
#pragma unroll
    for (int e = 0; e < NE; e++) { p[e] = __expf(acc[e] - m); s += p[e]; }
    float inv = 1.f / s;
    int e0 = 0;
#pragma unroll
    for (int e = 1; e < NE; e++) if (acc[e] > acc[e0]) e0 = e;
    int e1 = (e0 == 0) ? 1 : 0;
#pragma unroll
    for (int e = 0; e < NE; e++) if (e != e0 && acc[e] > acc[e1]) e1 = e;
    float p0 = p[e0] * inv, p1 = p[e1] * inv;
    float rn = 1.f / (p0 + p1);
    tki[2 * t] = e0; tki[2 * t + 1] = e1;
    tkp[2 * t] = p0 * rn; tkp[2 * t + 1] = p1 * rn;
    float4 pa = {p[0] * inv, p[1] * inv, p[2] * inv, p[3] * inv};
    float4 pb = {p[4] * inv, p[5] * inv, p[6] * inv, p[7] * inv};
    ((float4*)(probs + t * 8))[0] = pa;
    ((float4*)(probs + t * 8))[1] = pb;
    float lse = __logf(s) + m;
    lse2[t] = lse * lse;
  }
}

// ---------------- reduce router stats ----------------
__global__ __launch_bounds__(1024) void reduce_router_kernel(
    const int* __restrict__ tki, const float* __restrict__ probs, const float* __restrict__ lse2,
    int* __restrict__ fcnt, float* __restrict__ psum, float* __restrict__ zsum) {
  int t = blockIdx.x * 1024 + threadIdx.x;
  float4 pa = ((const float4*)(probs + t * 8))[0];
  float4 pb = ((const float4*)(probs + t * 8))[1];
  float p[8] = {pa.x, pa.y, pa.z, pa.w, pb.x, pb.y, pb.z, pb.w};
  float z = lse2[t];
  int e0 = tki[2 * t], e1 = tki[2 * t + 1];
  int fc[8];
#pragma unroll
  for (int e = 0; e < 8; e++) fc[e] = (e0 == e ? 1 : 0) + (e1 == e ? 1 : 0);
#pragma unroll
  for (int off = 32; off > 0; off >>= 1) {
#pragma unroll
    for (int e = 0; e < 8; e++) { p[e] += __shfl_xor(p[e], off); fc[e] += __shfl_xor(fc[e], off); }
    z += __shfl_xor(z, off);
  }
  __shared__ float sp[16][9];
  __shared__ int sf[16][8];
  int wv = threadIdx.x >> 6, lane = threadIdx.x & 63;
  if (lane == 0) {
#pragma unroll
    for (int e = 0; e < 8; e++) { sp[wv][e] = p[e]; sf[wv][e] = fc[e]; }
    sp[wv][8] = z;
  }
  __syncthreads();
  if (threadIdx.x < 9) {
    float s = 0.f;
    for (int w = 0; w < 16; w++) s += sp[w][threadIdx.x];
    if (threadIdx.x < 8) atomicAdd(&psum[threadIdx.x], s);
    else atomicAdd(zsum, s);
  }
  if (threadIdx.x >= 64 && threadIdx.x < 72) {
    int e = threadIdx.x - 64;
    int s = 0;
    for (int w = 0; w < 16; w++) s += sf[w][e];
    atomicAdd(&fcnt[e], s);
  }
}

// ---------------- rank + dispatch: deterministic positions, NO atomics ----------------
__global__ __launch_bounds__(1024) void rank_dispatch_kernel(
    const int* __restrict__ tki, const float* __restrict__ tkp,
    int* __restrict__ ltk, float* __restrict__ lw,
    int* __restrict__ counts, int* __restrict__ baserow, int* __restrict__ kflags) {
  __shared__ int wave_cnt[2][16][8];
  __shared__ int base[2][8];
  __shared__ int sc0[8];
  int tid = threadIdx.x, wv = tid >> 6, lane = tid & 63;
  int c0w[8];
#pragma unroll
  for (int e = 0; e < 8; e++) c0w[e] = 0;
  for (int c = 0; c < T_TOK / 1024; c++) {
    int e0 = tki[2 * (c * 1024 + tid)];
#pragma unroll
    for (int e = 0; e < 8; e++) {
      u64 m = __ballot(e0 == e);
      if (lane == 0) c0w[e] += __popcll(m);
    }
  }
  if (lane == 0) {
#pragma unroll
    for (int e = 0; e < 8; e++) wave_cnt[0][wv][e] = c0w[e];
  }
  if (tid < 16) base[tid >> 3][tid & 7] = 0;
  __syncthreads();
  if (tid < 8) {
    int s = 0;
    for (int w = 0; w < 16; w++) s += wave_cnt[0][w][tid];
    sc0[tid] = (s < CAP) ? s : CAP;
  }
  __syncthreads();
  u64 lmask = (lane == 63) ? 0x7FFFFFFFFFFFFFFFull : ((1ull << lane) - 1ull);
  for (int c = 0; c < T_TOK / 1024; c++) {
    int t = c * 1024 + tid;
    int e0 = tki[2 * t], e1 = tki[2 * t + 1];
    float p0 = tkp[2 * t], p1 = tkp[2 * t + 1];
    int pre0 = 0, pre1 = 0;
    for (int e = 0; e < 8; e++) {
      u64 m0 = __ballot(e0 == e);
      if (e0 == e) pre0 = __popcll(m0 & lmask);
      if (lane == 0) wave_cnt[0][wv][e] = __popcll(m0);
      u64 m1 = __ballot(e1 == e);
      if (e1 == e) pre1 = __popcll(m1 & lmask);
      if (lane == 0) wave_cnt[1][wv][e] = __popcll(m1);
    }
    __syncthreads();
    if (tid < 16) {
      int k = tid >> 3, e = tid & 7;
      int run = base[k][e];
      for (int w = 0; w < 16; w++) {
        int v = wave_cnt[k][w][e];
        wave_cnt[k][w][e] = run;
        run += v;
      }
      base[k][e] = run;
    }
    __syncthreads();
    int r0 = wave_cnt[0][wv][e0] + pre0;
    int r1 = wave_cnt[1][wv][e1] + pre1;
    if (r0 < CAP) { ltk[e0 * LSTR + r0] = (t << 1); lw[e0 * LSTR + r0] = p0; }
    if (r1 < CAP) {
      int p = sc0[e1] + r1;
      ltk[e1 * LSTR + p] = (t << 1) | 1; lw[e1 * LSTR + p] = p1;
    }
    kflags[t] = (r0 < CAP ? 1 : 0) | (r1 < CAP ? 2 : 0);
    __syncthreads();
  }
  if (tid == 0) {
    int run = 0;
    for (int e = 0; e < 8; e++) {
      int c1 = base[1][e]; if (c1 > CAP) c1 = CAP;
      int cnt = sc0[e] + c1;
      counts[e] = cnt; baserow[e] = run; run += cnt;
    }
  }
}

// ================= 8-phase 256x256 GEMM kernels =================
// Fragment load macros (XOR-swizzled LDS reads, BK=64 => kk slots quad / quad+4)
#define LOADA(MS, PB) \
  _Pragma("unroll") for (int i_ = 0; i_ < 4; i_++) { \
    const u16* rp_ = (PB) + ((MS) * 64 + i_ * 16 + lrow) * 64; \
    a[i_][0] = *(const s8v*)(rp_ + sx0); \
    a[i_][1] = *(const s8v*)(rp_ + sx1); }
#define LOADB(DST, NS, PB) \
  _Pragma("unroll") for (int j_ = 0; j_ < 2; j_++) { \
    const u16* rp_ = (PB) + (cb + (NS) * 32 + j_ * 16 + lrow) * 64; \
    DST[j_][0] = *(const s8v*)(rp_ + sx0); \
    DST[j_][1] = *(const s8v*)(rp_ + sx1); }
#define QMFMA(MS, NS, BREG) \
  _Pragma("unroll") for (int i_ = 0; i_ < 4; i_++) { \
    _Pragma("unroll") for (int j_ = 0; j_ < 2; j_++) { \
      acc[(MS) * 4 + i_][(NS) * 2 + j_] = __builtin_amdgcn_mfma_f32_16x16x32_bf16( \
          a[i_][0], BREG[j_][0], acc[(MS) * 4 + i_][(NS) * 2 + j_], 0, 0, 0); \
      acc[(MS) * 4 + i_][(NS) * 2 + j_] = __builtin_amdgcn_mfma_f32_16x16x32_bf16( \
          a[i_][1], BREG[j_][1], acc[(MS) * 4 + i_][(NS) * 2 + j_], 0, 0, 0); } }

// Staging: addresses precomputed (u32 element offsets vs kernel-arg bases).
#define STAGE_A(P, H, KT) do { \
    glds16(gAbase + (offA[H][0] + (u32)((KT) * 64)), aLds + ((P) * 2 + (H)) * 8192 + t8); \
    glds16(gAbase + (offA[H][1] + (u32)((KT) * 64)), aLds + ((P) * 2 + (H)) * 8192 + 4096 + t8); \
  } while (0)
#define STAGE_B(P, H, KT) do { \
    glds16(gBbase + (offB[H][0] + (u32)((KT) * 64)), bLds + ((P) * 2 + (H)) * 8192 + t8); \
    glds16(gBbase + (offB[H][1] + (u32)((KT) * 64)), bLds + ((P) * 2 + (H)) * 8192 + 4096 + t8); \
  } while (0)

// One K-tile, 4 quadrant phases; P compile-time (loop unrolled by 2).
// Deep pipeline: ALL 4 halves of tile KT+2 staged this tile (B at q2 after B[p]
// fully read, A at q3 after A[p] fully read). WAITV(8) at q3 waits only for
// tile KT+1's halves (staged during tile KT-1, 4-8 phases old) -- the 8 loads
// of KT+2 stay in flight across the barrier.
#define KTILE(KT, P, NK) do { \
    const u16* Ap = Awb + (P) * 16384; \
    const u16* Bp = Bwb + (P) * 16384; \
    LOADA(0, Ap); \
    LOADB(b0, 0, Bp); \
    BARRIER(); WAITL(); \
    PRIO1; QMFMA(0, 0, b0); PRIO0; \
    BARRIER(); \
    LOADB(b1, 1, Bp); \
    BARRIER(); WAITL(); \
    PRIO1; QMFMA(0, 1, b1); PRIO0; \
    BARRIER(); \
    LOADA(1, Ap); \
    if ((KT) + 2 < (NK)) { STAGE_B(P, 0, (KT) + 2); STAGE_B(P, 1, (KT) + 2); } \
    BARRIER(); WAITL(); \
    PRIO1; QMFMA(1, 1, b1); PRIO0; \
    BARRIER(); \
    if ((KT) + 2 < (NK)) { STAGE_A(P, 0, (KT) + 2); STAGE_A(P, 1, (KT) + 2); } \
    if ((KT) < (NK) - 2) { WAITV(8); } else { WAITV(0); } \
    BARRIER(); \
    PRIO1; QMFMA(1, 0, b0); PRIO0; \
    BARRIER(); \
  } while (0)

// ---------------- GEMM1: H = silu(x@Wg^T) * (x@Wu^T) ----------------
// BM=256 tokens, Wcat-N=256 (=128 H cols, gate/up interleaved by 16 rows), BK=64, NK=12
__global__ __launch_bounds__(512, 2) void gemm1_kernel(
    const u16* __restrict__ xb, const u16* __restrict__ wgb, const u16* __restrict__ wub,
    u16* __restrict__ H, const int* __restrict__ counts, const int* __restrict__ baserow,
    const int* __restrict__ ltk) {
  int id = blockIdx.x;
  int wgi = (id & 7) * 240 + (id >> 3);
  int e = wgi / 240;
  int rem = wgi - e * 240;
  int NT = rem / 10;          // [0,24) Wcat 256-col tile
  int mt = rem - NT * 10;     // [0,10)
  int cnt = counts[e];
  if (mt * 256 >= cnt) return;

  __shared__ u16 A[2][2][128 * 64];
  __shared__ u16 B[2][2][128 * 64];
  __shared__ int toks[256];
  int tid = threadIdx.x;
  if (tid < 256) {
    int r = mt * 256 + tid; if (r > cnt - 1) r = cnt - 1;
    toks[tid] = ltk[e * LSTR + r] >> 1;
  }
  __syncthreads();

  // ---- precompute staging offsets (u32 elements vs bases) ----
  const u16* gAbase = xb;
  const u16* gBbase = wgb;                 // wub = wgb + NE*FF*DIM in workspace
  u16* aLds = &A[0][0][0];
  u16* bLds = &B[0][0][0];
  int t8 = tid * 8;
  int row0 = tid >> 3, row1 = row0 + 64;   // chunk rows within a 128-row half
  int lsw = ((tid & 7) ^ (row0 & 7)) * 8;  // inverse-swizzled 16B slot (row1&7==row0&7)
  u32 offA[2][2], offB[2][2];
#pragma unroll
  for (int h = 0; h < 2; h++) {
    offA[h][0] = (u32)toks[h * 128 + row0] * DIM + lsw;
    offA[h][1] = (u32)toks[h * 128 + row1] * DIM + lsw;
#pragma unroll
    for (int c = 0; c < 2; c++) {
      int rowc = c ? row1 : row0;
      int rr = NT * 256 + h * 128 + rowc;           // Wcat row
      int f = ((rr >> 5) << 4) + (rr & 15);         // FF row within expert
      u32 o = (u32)(e * FF + f) * DIM + lsw;
      if ((rr >> 4) & 1) o += (u32)NE * FF * DIM;   // up-projection half
      offB[h][c] = o;
    }
  }

  int lane = tid & 63, wv = tid >> 6;
  int wm = (wv & 1) * 128;    // wave A-half
  int wn = (wv >> 1) * 64;    // wave B 64-col range
  int lrow = lane & 15, quad = lane >> 4;
  int cb = wn & 64;
  int sx0 = (quad ^ (lrow & 7)) * 8;
  int sx1 = ((quad + 4) ^ (lrow & 7)) * 8;
  const u16* Awb = &A[0][wm >> 7][0];
  const u16* Bwb = &B[0][wn >> 7][0];

  f4v acc[8][4];
#pragma unroll
  for (int i = 0; i < 8; i++)
#pragma unroll
    for (int j = 0; j < 4; j++) acc[i][j] = (f4v){0.f, 0.f, 0.f, 0.f};
  s8v a[4][2], b0[2][2], b1[2][2];

  // prologue: tiles 0 and 1 fully staged; wait tile0 (8 newest = tile1 in flight)
  STAGE_A(0, 0, 0); STAGE_A(0, 1, 0); STAGE_B(0, 0, 0); STAGE_B(0, 1, 0);
  STAGE_A(1, 0, 1); STAGE_A(1, 1, 1); STAGE_B(1, 0, 1); STAGE_B(1, 1, 1);
  WAITV(8);
  BARRIER();

#pragma unroll 1
  for (int kt = 0; kt < 12; kt += 2) {
    KTILE(kt, 0, 12);
    KTILE(kt + 1, 1, 12);
  }

  long hb = (long)baserow[e] + (long)mt * 256;
#pragma unroll
  for (int mi = 0; mi < 8; mi++) {
#pragma unroll
    for (int r4 = 0; r4 < 4; r4++) {
      int m = wm + (mi >> 2) * 64 + (mi & 3) * 16 + quad * 4 + r4;
      if (mt * 256 + m < cnt) {
#pragma unroll
        for (int pr = 0; pr < 2; pr++) {
          float gv = acc[mi][pr * 2][r4], uv = acc[mi][pr * 2 + 1][r4];
          float h = gv / (1.f + __expf(-gv)) * uv;
          H[(hb + m) * FF + NT * 128 + (wn >> 1) + pr * 16 + lrow] = f2bf(h);
        }
      }
    }
  }
}

// ---------------- GEMM2: ybuf[(t,k)] = (H @ wo^T) * w ----------------
// BM=256 H rows, BN=256 DIM cols (nt in {0,1,2}), BK=64, NK=48
__global__ __launch_bounds__(512, 2) void gemm2_kernel(
    const u16* __restrict__ Hsrc, const u16* __restrict__ wob,
    float* __restrict__ ybuf, const int* __restrict__ counts, const int* __restrict__ baserow,
    const int* __restrict__ ltk, const float* __restrict__ lw) {
  int id = blockIdx.x;
  int wgi = (id & 7) * 30 + (id >> 3);
  int e = wgi / 30;
  int rem = wgi - e * 30;
  int mt = rem / 3;
  int nt = rem - mt * 3;
  int cnt = counts[e];
  if (mt * 256 >= cnt) return;

  __shared__ u16 A[2][2][128 * 64];
  __shared__ u16 B[2][2][128 * 64];
  __shared__ int stok[256];
  __shared__ float sw[256];
  int tid = threadIdx.x;
  if (tid < 256) {
    int r = mt * 256 + tid; if (r > cnt - 1) r = cnt - 1;
    stok[tid] = ltk[e * LSTR + r];
    sw[tid] = lw[e * LSTR + r];
  }
  __syncthreads();
  int hb0 = baserow[e];

  // ---- precompute staging offsets ----
  const u16* gAbase = Hsrc;
  const u16* gBbase = wob;
  u16* aLds = &A[0][0][0];
  u16* bLds = &B[0][0][0];
  int t8 = tid * 8;
  int row0 = tid >> 3, row1 = row0 + 64;
  int lsw = ((tid & 7) ^ (row0 & 7)) * 8;
  u32 offA[2][2], offB[2][2];
#pragma unroll
  for (int h = 0; h < 2; h++) {
#pragma unroll
    for (int c = 0; c < 2; c++) {
      int rowc = c ? row1 : row0;
      int r_ = mt * 256 + h * 128 + rowc; if (r_ > cnt - 1) r_ = cnt - 1;
      offA[h][c] = (u32)(hb0 + r_) * FF + lsw;
      offB[h][c] = (u32)(e * DIM + nt * 256 + h * 128 + rowc) * FF + lsw;
    }
  }

  int lane = tid & 63, wv = tid >> 6;
  int wm = (wv & 1) * 128;
  int wn = (wv >> 1) * 64;
  int lrow = lane & 15, quad = lane >> 4;
  int cb = wn & 64;
  int sx0 = (quad ^ (lrow & 7)) * 8;
  int sx1 = ((quad + 4) ^ (lrow & 7)) * 8;
  const u16* Awb = &A[0][wm >> 7][0];
  const u16* Bwb = &B[0][wn >> 7][0];

  f4v acc[8][4];
#pragma unroll
  for (int i = 0; i < 8; i++)
#pragma unroll
    for (int j = 0; j < 4; j++) acc[i][j] = (f4v){0.f, 0.f, 0.f, 0.f};
  s8v a[4][2], b0[2][2], b1[2][2];

  STAGE_A(0, 0, 0); STAGE_A(0, 1, 0); STAGE_B(0, 0, 0); STAGE_B(0, 1, 0);
  STAGE_A(1, 0, 1); STAGE_A(1, 1, 1); STAGE_B(1, 0, 1); STAGE_B(1, 1, 1);
  WAITV(8);
  BARRIER();

#pragma unroll 1
  for (int kt = 0; kt < 48; kt += 2) {
    KTILE(kt, 0, 48);
    KTILE(kt + 1, 1, 48);
  }

#pragma unroll
  for (int mi = 0; mi < 8; mi++) {
#pragma unroll
    for (int r4 = 0; r4 < 4; r4++) {
      int m = wm + (mi >> 2) * 64 + (mi & 3) * 16 + quad * 4 + r4;
      if (mt * 256 + m < cnt) {
        int entry = stok[m];
        float w = sw[m];
        long ob = (long)entry * DIM + nt * 256 + wn;
#pragma unroll
        for (int jc = 0; jc < 4; jc++)
          ybuf[ob + jc * 16 + lrow] = acc[mi][jc][r4] * w;
      }
    }
  }
}

// ---------------- combine: out[t] = sum of kept (t,k) contributions ----------------
__global__ __launch_bounds__(256) void combine_kernel(
    const float* __restrict__ ybuf, const int* __restrict__ kflags, float* __restrict__ out) {
  int idx = blockIdx.x * 256 + threadIdx.x;   // [0, T*DIM/4)
  int t = idx / (DIM / 4);
  int d4 = idx - t * (DIM / 4);
  int kf = kflags[t];
  float4 r = {0.f, 0.f, 0.f, 0.f};
  if (kf & 1) {
    float4 a = ((const float4*)(ybuf + (long)(2 * t) * DIM))[d4];
    r.x += a.x; r.y += a.y; r.z += a.z; r.w += a.w;
  }
  if (kf & 2) {
    float4 b = ((const float4*)(ybuf + (long)(2 * t + 1) * DIM))[d4];
    r.x += b.x; r.y += b.y; r.z += b.z; r.w += b.w;
  }
  ((float4*)out)[idx] = r;
}

// ---------------- aux loss ----------------
__global__ void aux_kernel(const int* __restrict__ fcnt, const float* __restrict__ psum,
                           const float* __restrict__ zsum, float* __restrict__ outaux) {
  if (threadIdx.x == 0 && blockIdx.x == 0) {
    float lb = 0.f;
    for (int e = 0; e < 8; e++)
      lb += ((float)fcnt[e] / (float)(T_TOK * 2)) * (psum[e] / (float)T_TOK);
    lb *= 8.f;
    float z = zsum[0] / (float)T_TOK;
    outaux[0] = 0.01f * lb + 0.001f * z;
  }
}

extern "C" void kernel_launch(void* const* d_in, const int* in_sizes, int n_in,
                              void* d_out, int out_size, void* d_ws, size_t ws_size,
                              hipStream_t stream) {
  const float* x = (const float*)d_in[0];
  const float* wgate = (const float*)d_in[1];
  const float* wig = (const float*)d_in[2];
  const float* wiu = (const float*)d_in[3];
  const float* wo = (const float*)d_in[4];
  float* out = (float*)d_out;

  char* ws = (char*)d_ws;
  size_t off = 0;
  auto alloc = [&](size_t bytes) {
    void* p = ws + off;
    off += (bytes + 255) & ~(size_t)255;
    return p;
  };
  int* ctrl = (int*)alloc(256);
  u16* xb = (u16*)alloc((size_t)T_TOK * DIM * 2);
  u16* wgb = (u16*)alloc((size_t)NE * FF * DIM * 2);
  u16* wub = (u16*)alloc((size_t)NE * FF * DIM * 2);   // MUST stay contiguous after wgb
  u16* wob = (u16*)alloc((size_t)NE * DIM * FF * 2);
  u16* Hbuf = (u16*)alloc((size_t)(T_TOK * 2 + 256) * FF * 2);
  int* tki = (int*)alloc((size_t)T_TOK * 2 * 4);
  float* tkp = (float*)alloc((size_t)T_TOK * 2 * 4);
  int* ltk = (int*)alloc((size_t)NE * LSTR * 4);
  float* lw = (float*)alloc((size_t)NE * LSTR * 4);
  float* probs = (float*)alloc((size_t)T_TOK * 8 * 4);
  float* lse2 = (float*)alloc((size_t)T_TOK * 4);
  int* kflags = (int*)alloc((size_t)T_TOK * 4);
  // ybuf [T*2, DIM] fp32 (50.3MB) aliases wgb+wub (75.5MB): weights dead after gemm1
  float* ybuf = (float*)wgb;

  int* fcnt = ctrl;
  int* counts = ctrl + 8;
  int* baserow = ctrl + 16;
  float* psum = (float*)(ctrl + 24);
  float* zsum = (float*)(ctrl + 32);

  const int n8each = NE * FF * DIM / 8;
  hipMemsetAsync(ctrl, 0, 256, stream);
  pre_kernel<<<NCAST + T_TOK / 4, 256, 0, stream>>>(
      wig, wiu, wo, wgb, wub, wob, n8each, x, wgate, xb, tki, tkp, probs, lse2);
  reduce_router_kernel<<<T_TOK / 1024, 1024, 0, stream>>>(tki, probs, lse2, fcnt, psum, zsum);
  rank_dispatch_kernel<<<1, 1024, 0, stream>>>(tki, tkp, ltk, lw, counts, baserow, kflags);
  gemm1_kernel<<<1920, 512, 0, stream>>>(xb, wgb, wub, Hbuf, counts, baserow, ltk);
  gemm2_kernel<<<240, 512, 0, stream>>>(Hbuf, wob, ybuf, counts, baserow, ltk, lw);
  combine_kernel<<<T_TOK * DIM / 4 / 256, 256, 0, stream>>>(ybuf, kflags, out);
  aux_kernel<<<1, 64, 0, stream>>>(fcnt, psum, zsum, out + (size_t)T_TOK * DIM);
}

// Round 7
// 577.499 us; speedup vs baseline: 1.0848x; 1.0848x over previous
//
#include <hip/hip_runtime.h>

typedef unsigned short u16;
typedef unsigned int u32;
typedef unsigned long long u64;

#define T_TOK 8192
#define DIM 768
#define FF 3072
#define NE 8
#define CAP 2560
#define LSTR 5120
#define MAXMT 20
#define NCAST 27648  // 3 * (NE*FF*DIM/8) / 256 cast blocks

typedef __attribute__((ext_vector_type(8))) short s8v;
typedef __attribute__((ext_vector_type(4))) float f4v;

__device__ __forceinline__ u16 f2bf(float f) {
  union { float f; u32 u; } v; v.f = f;
  u32 r = v.u + 0x7FFFu + ((v.u >> 16) & 1u);
  return (u16)(r >> 16);
}

__device__ __forceinline__ void glds16(const void* g, void* l) {
  __builtin_amdgcn_global_load_lds(
      (const __attribute__((address_space(1))) u32*)g,
      (__attribute__((address_space(3))) u32*)l, 16, 0, 0);
}

// ---------------- fused: weight casts (blocks 0..NCAST-1) + router (rest) ----------------
__global__ __launch_bounds__(256) void pre_kernel(
    const float* __restrict__ wig, const float* __restrict__ wiu, const float* __restrict__ wo,
    u16* __restrict__ wgb, u16* __restrict__ wub, u16* __restrict__ wob, int n8each,
    const float* __restrict__ x, const float* __restrict__ wg, u16* __restrict__ xb,
    int* __restrict__ tki, float* __restrict__ tkp,
    float* __restrict__ probs, float* __restrict__ lse2) {
  int bid = blockIdx.x;
  if (bid < NCAST) {
    int i = bid * 256 + threadIdx.x;
    const float* s; u16* d; int j;
    if (i < n8each) { s = wig; d = wgb; j = i; }
    else if (i < 2 * n8each) { s = wiu; d = wub; j = i - n8each; }
    else { s = wo; d = wob; j = i - 2 * n8each; }
    const float4* s4 = (const float4*)s;
    float4 a = s4[2 * j], b = s4[2 * j + 1];
    uint4 o;
    o.x = (u32)f2bf(a.x) | ((u32)f2bf(a.y) << 16);
    o.y = (u32)f2bf(a.z) | ((u32)f2bf(a.w) << 16);
    o.z = (u32)f2bf(b.x) | ((u32)f2bf(b.y) << 16);
    o.w = (u32)f2bf(b.z) | ((u32)f2bf(b.w) << 16);
    ((uint4*)d)[j] = o;
    return;
  }
  int rb = bid - NCAST;
  int lane = threadIdx.x & 63;
  int t = rb * 4 + (threadIdx.x >> 6);
  const float* xr = x + (long)t * DIM;
  u16* xw = xb + (long)t * DIM;
  float acc[NE];
#pragma unroll
  for (int e = 0; e < NE; e++) acc[e] = 0.f;
  for (int i = 0; i < DIM / 64; i++) {
    float xv = xr[lane + 64 * i];
    xw[lane + 64 * i] = f2bf(xv);
#pragma unroll
    for (int e = 0; e < NE; e++) acc[e] += xv * wg[e * DIM + lane + 64 * i];
  }
#pragma unroll
  for (int off = 32; off > 0; off >>= 1) {
#pragma unroll
    for (int e = 0; e < NE; e++) acc[e] += __shfl_xor(acc[e], off);
  }
  if (lane == 0) {
    float m = acc[0];
#pragma unroll
    for (int e = 1; e < NE; e++) m = fmaxf(m, acc[e]);
    float p[NE], s = 0.f;
#pragma unroll
    for (int e = 0; e < NE; e++) { p[e] = __expf(acc[e] - m); s += p[e]; }
    float inv = 1.f / s;
    int e0 = 0;
#pragma unroll
    for (int e = 1; e < NE; e++) if (acc[e] > acc[e0]) e0 = e;
    int e1 = (e0 == 0) ? 1 : 0;
#pragma unroll
    for (int e = 0; e < NE; e++) if (e != e0 && acc[e] > acc[e1]) e1 = e;
    float p0 = p[e0] * inv, p1 = p[e1] * inv;
    float rn = 1.f / (p0 + p1);
    tki[2 * t] = e0; tki[2 * t + 1] = e1;
    tkp[2 * t] = p0 * rn; tkp[2 * t + 1] = p1 * rn;
    float4 pa = {p[0] * inv, p[1] * inv, p[2] * inv, p[3] * inv};
    float4 pb = {p[4] * inv, p[5] * inv, p[6] * inv, p[7] * inv};
    ((float4*)(probs + t * 8))[0] = pa;
    ((float4*)(probs + t * 8))[1] = pb;
    float lse = __logf(s) + m;
    lse2[t] = lse * lse;
  }
}

// ---------------- reduce router stats ----------------
__global__ __launch_bounds__(1024) void reduce_router_kernel(
    const int* __restrict__ tki, const float* __restrict__ probs, const float* __restrict__ lse2,
    int* __restrict__ fcnt, float* __restrict__ psum, float* __restrict__ zsum) {
  int t = blockIdx.x * 1024 + threadIdx.x;
  float4 pa = ((const float4*)(probs + t * 8))[0];
  float4 pb = ((const float4*)(probs + t * 8))[1];
  float p[8] = {pa.x, pa.y, pa.z, pa.w, pb.x, pb.y, pb.z, pb.w};
  float z = lse2[t];
  int e0 = tki[2 * t], e1 = tki[2 * t + 1];
  int fc[8];
#pragma unroll
  for (int e = 0; e < 8; e++) fc[e] = (e0 == e ? 1 : 0) + (e1 == e ? 1 : 0);
#pragma unroll
  for (int off = 32; off > 0; off >>= 1) {
#pragma unroll
    for (int e = 0; e < 8; e++) { p[e] += __shfl_xor(p[e], off); fc[e] += __shfl_xor(fc[e], off); }
    z += __shfl_xor(z, off);
  }
  __shared__ float sp[16][9];
  __shared__ int sf[16][8];
  int wv = threadIdx.x >> 6, lane = threadIdx.x & 63;
  if (lane == 0) {
#pragma unroll
    for (int e = 0; e < 8; e++) { sp[wv][e] = p[e]; sf[wv][e] = fc[e]; }
    sp[wv][8] = z;
  }
  __syncthreads();
  if (threadIdx.x < 9) {
    float s = 0.f;
    for (int w = 0; w < 16; w++) s += sp[w][threadIdx.x];
    if (threadIdx.x < 8) atomicAdd(&psum[threadIdx.x], s);
    else atomicAdd(zsum, s);
  }
  if (threadIdx.x >= 64 && threadIdx.x < 72) {
    int e = threadIdx.x - 64;
    int s = 0;
    for (int w = 0; w < 16; w++) s += sf[w][e];
    atomicAdd(&fcnt[e], s);
  }
}

// ---------------- rank + dispatch: deterministic positions, NO atomics ----------------
__global__ __launch_bounds__(1024) void rank_dispatch_kernel(
    const int* __restrict__ tki, const float* __restrict__ tkp,
    int* __restrict__ ltk, float* __restrict__ lw,
    int* __restrict__ counts, int* __restrict__ baserow, int* __restrict__ kflags) {
  __shared__ int wave_cnt[2][16][8];
  __shared__ int base[2][8];
  __shared__ int sc0[8];
  int tid = threadIdx.x, wv = tid >> 6, lane = tid & 63;
  int c0w[8];
#pragma unroll
  for (int e = 0; e < 8; e++) c0w[e] = 0;
  for (int c = 0; c < T_TOK / 1024; c++) {
    int e0 = tki[2 * (c * 1024 + tid)];
#pragma unroll
    for (int e = 0; e < 8; e++) {
      u64 m = __ballot(e0 == e);
      if (lane == 0) c0w[e] += __popcll(m);
    }
  }
  if (lane == 0) {
#pragma unroll
    for (int e = 0; e < 8; e++) wave_cnt[0][wv][e] = c0w[e];
  }
  if (tid < 16) base[tid >> 3][tid & 7] = 0;
  __syncthreads();
  if (tid < 8) {
    int s = 0;
    for (int w = 0; w < 16; w++) s += wave_cnt[0][w][tid];
    sc0[tid] = (s < CAP) ? s : CAP;
  }
  __syncthreads();
  u64 lmask = (lane == 63) ? 0x7FFFFFFFFFFFFFFFull : ((1ull << lane) - 1ull);
  for (int c = 0; c < T_TOK / 1024; c++) {
    int t = c * 1024 + tid;
    int e0 = tki[2 * t], e1 = tki[2 * t + 1];
    float p0 = tkp[2 * t], p1 = tkp[2 * t + 1];
    int pre0 = 0, pre1 = 0;
    for (int e = 0; e < 8; e++) {
      u64 m0 = __ballot(e0 == e);
      if (e0 == e) pre0 = __popcll(m0 & lmask);
      if (lane == 0) wave_cnt[0][wv][e] = __popcll(m0);
      u64 m1 = __ballot(e1 == e);
      if (e1 == e) pre1 = __popcll(m1 & lmask);
      if (lane == 0) wave_cnt[1][wv][e] = __popcll(m1);
    }
    __syncthreads();
    if (tid < 16) {
      int k = tid >> 3, e = tid & 7;
      int run = base[k][e];
      for (int w = 0; w < 16; w++) {
        int v = wave_cnt[k][w][e];
        wave_cnt[k][w][e] = run;
        run += v;
      }
      base[k][e] = run;
    }
    __syncthreads();
    int r0 = wave_cnt[0][wv][e0] + pre0;
    int r1 = wave_cnt[1][wv][e1] + pre1;
    if (r0 < CAP) { ltk[e0 * LSTR + r0] = (t << 1); lw[e0 * LSTR + r0] = p0; }
    if (r1 < CAP) {
      int p = sc0[e1] + r1;
      ltk[e1 * LSTR + p] = (t << 1) | 1; lw[e1 * LSTR + p] = p1;
    }
    kflags[t] = (r0 < CAP ? 1 : 0) | (r1 < CAP ? 2 : 0);
    __syncthreads();
  }
  if (tid == 0) {
    int run = 0;
    for (int e = 0; e < 8; e++) {
      int c1 = base[1][e]; if (c1 > CAP) c1 = CAP;
      int cnt = sc0[e] + c1;
      counts[e] = cnt; baserow[e] = run; run += cnt;
    }
  }
}

// ---------------- GEMM1: H = silu(x@Wg^T) * (x@Wu^T), tile 128x64, BK=64, XOR-swizzled LDS ----------------
__global__ __launch_bounds__(256, 2) void gemm1_kernel(
    const u16* __restrict__ xb, const u16* __restrict__ wgb, const u16* __restrict__ wub,
    u16* __restrict__ H, const int* __restrict__ counts, const int* __restrict__ baserow,
    const int* __restrict__ ltk) {
  // swizzle: groups g=(e*48+nt) share weights; members mt on same XCD
  int id = blockIdx.x;
  int xcd = id & 7;
  int q = id >> 3;          // [0, 960)
  int gg = q / MAXMT;       // [0, 48)
  int mt = q - gg * MAXMT;  // [0, 20)
  int g = gg * 8 + xcd;     // [0, 384)
  int e = g / 48;
  int nt = g - e * 48;      // [0, 48)
  int cnt = counts[e];
  if (mt * 128 >= cnt) return;

  __shared__ u16 As[128 * 64];
  __shared__ u16 Bg[64 * 64];
  __shared__ u16 Bu[64 * 64];
  __shared__ int toks[128];
  int tid = threadIdx.x;
  if (tid < 128) {
    int r = mt * 128 + tid; if (r > cnt - 1) r = cnt - 1;
    toks[tid] = ltk[e * LSTR + r] >> 1;
  }
  __syncthreads();
  // staging: each thread loads 16B; row = tid>>3 (32 rows/call), slot = tid&7.
  // LDS dest LINEAR (global_load_lds constraint); global SOURCE inverse-swizzled.
  int rq8 = tid >> 3;                     // [0,32)
  int swz = ((tid & 7) ^ (rq8 & 7)) * 8;  // swizzled 8xu16 chunk within 64-col row
  long tA0 = toks[rq8], tA1 = toks[32 + rq8], tA2 = toks[64 + rq8], tA3 = toks[96 + rq8];
  const u16* gA0 = xb + tA0 * DIM + swz;
  const u16* gA1 = xb + tA1 * DIM + swz;
  const u16* gA2 = xb + tA2 * DIM + swz;
  const u16* gA3 = xb + tA3 * DIM + swz;
  long bO0 = ((long)e * FF + nt * 64 + rq8) * DIM + swz;
  long bO1 = bO0 + 32l * DIM;
  const u16* gG0 = wgb + bO0; const u16* gG1 = wgb + bO1;
  const u16* gU0 = wub + bO0; const u16* gU1 = wub + bO1;
  u16* dA0 = As + tid * 8; u16* dA1 = dA0 + 2048; u16* dA2 = dA0 + 4096; u16* dA3 = dA0 + 6144;
  u16* dG0 = Bg + tid * 8; u16* dG1 = dG0 + 2048;
  u16* dU0 = Bu + tid * 8; u16* dU1 = dU0 + 2048;

  int lane = tid & 63, wv = tid >> 6;
  int wm = (wv & 1) * 64, wn = (wv >> 1) * 32;
  int lrow = lane & 15, quad = lane >> 4;
  // read-side swizzle: logical slot (quad + kk*4) ^ (row&7); row&7 == lrow&7
  int sl0 = (quad ^ (lrow & 7)) * 8;
  int sl1 = ((quad + 4) ^ (lrow & 7)) * 8;

  f4v zero = {0.f, 0.f, 0.f, 0.f};
  f4v accg[4][2], accu[4][2];
#pragma unroll
  for (int i = 0; i < 4; i++)
#pragma unroll
    for (int j = 0; j < 2; j++) { accg[i][j] = zero; accu[i][j] = zero; }

  for (int kt = 0; kt < DIM / 64; kt++) {
    int ko = kt * 64;
    __syncthreads();
    glds16(gA0 + ko, dA0); glds16(gA1 + ko, dA1);
    glds16(gA2 + ko, dA2); glds16(gA3 + ko, dA3);
    glds16(gG0 + ko, dG0); glds16(gG1 + ko, dG1);
    glds16(gU0 + ko, dU0); glds16(gU1 + ko, dU1);
    __syncthreads();
#pragma unroll
    for (int kk = 0; kk < 2; kk++) {
      int sl = kk ? sl1 : sl0;
      s8v a[4], bgf[2], buf[2];
#pragma unroll
      for (int i = 0; i < 4; i++)
        a[i] = *(const s8v*)&As[(wm + i * 16 + lrow) * 64 + sl];
#pragma unroll
      for (int j = 0; j < 2; j++) {
        bgf[j] = *(const s8v*)&Bg[(wn + j * 16 + lrow) * 64 + sl];
        buf[j] = *(const s8v*)&Bu[(wn + j * 16 + lrow) * 64 + sl];
      }
#pragma unroll
      for (int i = 0; i < 4; i++)
#pragma unroll
        for (int j = 0; j < 2; j++) {
          accg[i][j] = __builtin_amdgcn_mfma_f32_16x16x32_bf16(a[i], bgf[j], accg[i][j], 0, 0, 0);
          accu[i][j] = __builtin_amdgcn_mfma_f32_16x16x32_bf16(a[i], buf[j], accu[i][j], 0, 0, 0);
        }
    }
  }
  long hb = (long)baserow[e] + (long)mt * 128;
#pragma unroll
  for (int i = 0; i < 4; i++) {
#pragma unroll
    for (int r = 0; r < 4; r++) {
      int m = wm + i * 16 + quad * 4 + r;
      if (mt * 128 + m < cnt) {
#pragma unroll
        for (int j = 0; j < 2; j++) {
          float gv = accg[i][j][r], uv = accu[i][j][r];
          float h = gv / (1.f + __expf(-gv)) * uv;
          H[(hb + m) * FF + nt * 64 + wn + j * 16 + lrow] = f2bf(h);
        }
      }
    }
  }
}

// ---------------- GEMM2: ybuf[(t,k)] = (H @ wo^T) * w, plain stores (no atomics) ----------------
__global__ __launch_bounds__(256, 2) void gemm2_kernel(
    const u16* __restrict__ H, const u16* __restrict__ wob,
    float* __restrict__ ybuf, const int* __restrict__ counts, const int* __restrict__ baserow,
    const int* __restrict__ ltk, const float* __restrict__ lw) {
  // swizzle: groups g=(e*20+mt) share H rows; members nt on same XCD
  int id = blockIdx.x;
  int xcd = id & 7;
  int q = id >> 3;        // [0, 120)
  int gg = q / 6;         // [0, 20)
  int nt = q - gg * 6;    // [0, 6)
  int g = gg * 8 + xcd;   // [0, 160)
  int e = g / MAXMT;
  int mt = g - e * MAXMT;
  int cnt = counts[e];
  if (mt * 128 >= cnt) return;

  __shared__ u16 As[128 * 64];
  __shared__ u16 Bs[128 * 64];
  __shared__ int stok[128];
  __shared__ float sw[128];
  int tid = threadIdx.x;
  if (tid < 128) {
    int r = mt * 128 + tid; if (r > cnt - 1) r = cnt - 1;
    stok[tid] = ltk[e * LSTR + r];
    sw[tid] = lw[e * LSTR + r];
  }
  long hb = (long)baserow[e] + (long)mt * 128;
  int rq8 = tid >> 3;
  int swz = ((tid & 7) ^ (rq8 & 7)) * 8;
  const u16* gA0 = H + (hb + rq8) * FF + swz;
  const u16* gA1 = gA0 + 32l * FF;
  const u16* gA2 = gA0 + 64l * FF;
  const u16* gA3 = gA0 + 96l * FF;
  long bOff = ((long)e * DIM + nt * 128 + rq8) * FF + swz;
  const u16* gB0 = wob + bOff;
  const u16* gB1 = gB0 + 32l * FF;
  const u16* gB2 = gB0 + 64l * FF;
  const u16* gB3 = gB0 + 96l * FF;
  u16* dA0 = As + tid * 8; u16* dA1 = dA0 + 2048; u16* dA2 = dA0 + 4096; u16* dA3 = dA0 + 6144;
  u16* dB0 = Bs + tid * 8; u16* dB1 = dB0 + 2048; u16* dB2 = dB0 + 4096; u16* dB3 = dB0 + 6144;
  int lane = tid & 63, wv = tid >> 6;
  int wm = (wv & 1) * 64, wn = (wv >> 1) * 64;
  int lrow = lane & 15, quad = lane >> 4;
  int sl0 = (quad ^ (lrow & 7)) * 8;
  int sl1 = ((quad + 4) ^ (lrow & 7)) * 8;
  f4v zero = {0.f, 0.f, 0.f, 0.f};
  f4v acc[4][4];
#pragma unroll
  for (int i = 0; i < 4; i++)
#pragma unroll
    for (int j = 0; j < 4; j++) acc[i][j] = zero;

  for (int kt = 0; kt < FF / 64; kt++) {
    int ko = kt * 64;
    __syncthreads();
    glds16(gA0 + ko, dA0); glds16(gA1 + ko, dA1);
    glds16(gA2 + ko, dA2); glds16(gA3 + ko, dA3);
    glds16(gB0 + ko, dB0); glds16(gB1 + ko, dB1);
    glds16(gB2 + ko, dB2); glds16(gB3 + ko, dB3);
    __syncthreads();
#pragma unroll
    for (int kk = 0; kk < 2; kk++) {
      int sl = kk ? sl1 : sl0;
      s8v a[4], b[4];
#pragma unroll
      for (int i = 0; i < 4; i++)
        a[i] = *(const s8v*)&As[(wm + i * 16 + lrow) * 64 + sl];
#pragma unroll
      for (int j = 0; j < 4; j++)
        b[j] = *(const s8v*)&Bs[(wn + j * 16 + lrow) * 64 + sl];
#pragma unroll
      for (int i = 0; i < 4; i++)
#pragma unroll
        for (int j = 0; j < 4; j++)
          acc[i][j] = __builtin_amdgcn_mfma_f32_16x16x32_bf16(a[i], b[j], acc[i][j], 0, 0, 0);
    }
  }
#pragma unroll
  for (int i = 0; i < 4; i++) {
#pragma unroll
    for (int r = 0; r < 4; r++) {
      int m = wm + i * 16 + quad * 4 + r;
      if (mt * 128 + m < cnt) {
        int entry = stok[m];       // (t<<1)|k  == ybuf row index
        float w = sw[m];
        long ob = (long)entry * DIM + nt * 128;
#pragma unroll
        for (int j = 0; j < 4; j++)
          ybuf[ob + wn + j * 16 + lrow] = acc[i][j][r] * w;
      }
    }
  }
}

// ---------------- combine: out[t] = sum of kept (t,k) contributions ----------------
__global__ __launch_bounds__(256) void combine_kernel(
    const float* __restrict__ ybuf, const int* __restrict__ kflags, float* __restrict__ out) {
  int idx = blockIdx.x * 256 + threadIdx.x;   // [0, T*DIM/4)
  int t = idx / (DIM / 4);
  int d4 = idx - t * (DIM / 4);
  int kf = kflags[t];
  float4 r = {0.f, 0.f, 0.f, 0.f};
  if (kf & 1) {
    float4 a = ((const float4*)(ybuf + (long)(2 * t) * DIM))[d4];
    r.x += a.x; r.y += a.y; r.z += a.z; r.w += a.w;
  }
  if (kf & 2) {
    float4 b = ((const float4*)(ybuf + (long)(2 * t + 1) * DIM))[d4];
    r.x += b.x; r.y += b.y; r.z += b.z; r.w += b.w;
  }
  ((float4*)out)[idx] = r;
}

// ---------------- aux loss ----------------
__global__ void aux_kernel(const int* __restrict__ fcnt, const float* __restrict__ psum,
                           const float* __restrict__ zsum, float* __restrict__ outaux) {
  if (threadIdx.x == 0 && blockIdx.x == 0) {
    float lb = 0.f;
    for (int e = 0; e < 8; e++)
      lb += ((float)fcnt[e] / (float)(T_TOK * 2)) * (psum[e] / (float)T_TOK);
    lb *= 8.f;
    float z = zsum[0] / (float)T_TOK;
    outaux[0] = 0.01f * lb + 0.001f * z;
  }
}

extern "C" void kernel_launch(void* const* d_in, const int* in_sizes, int n_in,
                              void* d_out, int out_size, void* d_ws, size_t ws_size,
                              hipStream_t stream) {
  const float* x = (const float*)d_in[0];
  const float* wgate = (const float*)d_in[1];
  const float* wig = (const float*)d_in[2];
  const float* wiu = (const float*)d_in[3];
  const float* wo = (const float*)d_in[4];
  float* out = (float*)d_out;

  char* ws = (char*)d_ws;
  size_t off = 0;
  auto alloc = [&](size_t bytes) {
    void* p = ws + off;
    off += (bytes + 255) & ~(size_t)255;
    return p;
  };
  int* ctrl = (int*)alloc(256);
  u16* xb = (u16*)alloc((size_t)T_TOK * DIM * 2);
  u16* wgb = (u16*)alloc((size_t)NE * FF * DIM * 2);
  u16* wub = (u16*)alloc((size_t)NE * FF * DIM * 2);
  u16* wob = (u16*)alloc((size_t)NE * DIM * FF * 2);
  u16* Hbuf = (u16*)alloc((size_t)(T_TOK * 2 + 128) * FF * 2);
  int* tki = (int*)alloc((size_t)T_TOK * 2 * 4);
  float* tkp = (float*)alloc((size_t)T_TOK * 2 * 4);
  int* ltk = (int*)alloc((size_t)NE * LSTR * 4);
  float* lw = (float*)alloc((size_t)NE * LSTR * 4);
  float* probs = (float*)alloc((size_t)T_TOK * 8 * 4);
  float* lse2 = (float*)alloc((size_t)T_TOK * 4);
  int* kflags = (int*)alloc((size_t)T_TOK * 4);
  // ybuf [T*2, DIM] fp32 (50.3MB) aliases wgb+wub (75.5MB): weights dead after gemm1
  float* ybuf = (float*)wgb;

  int* fcnt = ctrl;
  int* counts = ctrl + 8;
  int* baserow = ctrl + 16;
  float* psum = (float*)(ctrl + 24);
  float* zsum = (float*)(ctrl + 32);

  const int n8each = NE * FF * DIM / 8;
  hipMemsetAsync(ctrl, 0, 256, stream);
  pre_kernel<<<NCAST + T_TOK / 4, 256, 0, stream>>>(
      wig, wiu, wo, wgb, wub, wob, n8each, x, wgate, xb, tki, tkp, probs, lse2);
  reduce_router_kernel<<<T_TOK / 1024, 1024, 0, stream>>>(tki, probs, lse2, fcnt, psum, zsum);
  rank_dispatch_kernel<<<1, 1024, 0, stream>>>(tki, tkp, ltk, lw, counts, baserow, kflags);
  gemm1_kernel<<<8 * 48 * MAXMT, 256, 0, stream>>>(xb, wgb, wub, Hbuf, counts, baserow, ltk);
  gemm2_kernel<<<8 * MAXMT * 6, 256, 0, stream>>>(Hbuf, wob, ybuf, counts, baserow, ltk, lw);
  combine_kernel<<<T_TOK * DIM / 4 / 256, 256, 0, stream>>>(ybuf, kflags, out);
  aux_kernel<<<1, 64, 0, stream>>>(fcnt, psum, zsum, out + (size_t)T_TOK * DIM);
}

// Round 8
// 551.730 us; speedup vs baseline: 1.1354x; 1.0467x over previous
//
#include <hip/hip_runtime.h>

typedef unsigned short u16;
typedef unsigned int u32;
typedef unsigned long long u64;

#define T_TOK 8192
#define DIM 768
#define FF 3072
#define NE 8
#define CAP 2560
#define LSTR 5120
#define MAXMT 20
#define N8EACH 2359296          // NE*FF*DIM/8
#define NCAST2 18432            // 2*N8EACH/256 (wig+wiu cast blocks in pre)
#define NWOCAST 2304            // N8EACH/1024 (wo cast blocks in rankred)

typedef __attribute__((ext_vector_type(8))) short s8v;
typedef __attribute__((ext_vector_type(4))) float f4v;

__device__ __forceinline__ u16 f2bf(float f) {
  union { float f; u32 u; } v; v.f = f;
  u32 r = v.u + 0x7FFFu + ((v.u >> 16) & 1u);
  return (u16)(r >> 16);
}

__device__ __forceinline__ void glds16(const void* g, void* l) {
  __builtin_amdgcn_global_load_lds(
      (const __attribute__((address_space(1))) u32*)g,
      (__attribute__((address_space(3))) u32*)l, 16, 0, 0);
}

__device__ __forceinline__ void cast8(const float* __restrict__ s, u16* __restrict__ d, int j) {
  const float4* s4 = (const float4*)s;
  float4 a = s4[2 * j], b = s4[2 * j + 1];
  uint4 o;
  o.x = (u32)f2bf(a.x) | ((u32)f2bf(a.y) << 16);
  o.y = (u32)f2bf(a.z) | ((u32)f2bf(a.w) << 16);
  o.z = (u32)f2bf(b.x) | ((u32)f2bf(b.y) << 16);
  o.w = (u32)f2bf(b.z) | ((u32)f2bf(b.w) << 16);
  ((uint4*)d)[j] = o;
}

// ---------------- pre: wig/wiu casts (blocks 0..NCAST2-1) + router (rest); zeroes ctrl ----------------
__global__ __launch_bounds__(256) void pre_kernel(
    const float* __restrict__ wig, const float* __restrict__ wiu,
    u16* __restrict__ wgb, u16* __restrict__ wub,
    const float* __restrict__ x, const float* __restrict__ wg, u16* __restrict__ xb,
    int* __restrict__ tki, float* __restrict__ tkp,
    float* __restrict__ probs, float* __restrict__ lse2, int* __restrict__ ctrl) {
  int bid = blockIdx.x;
  if (bid == 0 && threadIdx.x < 64) ctrl[threadIdx.x] = 0;  // zero ctrl (fcnt/counts/psum/zsum)
  if (bid < NCAST2) {
    int i = bid * 256 + threadIdx.x;
    if (i < N8EACH) cast8(wig, wgb, i);
    else cast8(wiu, wub, i - N8EACH);
    return;
  }
  int rb = bid - NCAST2;
  int lane = threadIdx.x & 63;
  int t = rb * 4 + (threadIdx.x >> 6);
  const float* xr = x + (long)t * DIM;
  u16* xw = xb + (long)t * DIM;
  float acc[NE];
#pragma unroll
  for (int e = 0; e < NE; e++) acc[e] = 0.f;
  for (int i = 0; i < DIM / 64; i++) {
    float xv = xr[lane + 64 * i];
    xw[lane + 64 * i] = f2bf(xv);
#pragma unroll
    for (int e = 0; e < NE; e++) acc[e] += xv * wg[e * DIM + lane + 64 * i];
  }
#pragma unroll
  for (int off = 32; off > 0; off >>= 1) {
#pragma unroll
    for (int e = 0; e < NE; e++) acc[e] += __shfl_xor(acc[e], off);
  }
  if (lane == 0) {
    float m = acc[0];
#pragma unroll
    for (int e = 1; e < NE; e++) m = fmaxf(m, acc[e]);
    float p[NE], s = 0.f;
#pragma unroll
    for (int e = 0; e < NE; e++) { p[e] = __expf(acc[e] - m); s += p[e]; }
    float inv = 1.f / s;
    int e0 = 0;
#pragma unroll
    for (int e = 1; e < NE; e++) if (acc[e] > acc[e0]) e0 = e;
    int e1 = (e0 == 0) ? 1 : 0;
#pragma unroll
    for (int e = 0; e < NE; e++) if (e != e0 && acc[e] > acc[e1]) e1 = e;
    float p0 = p[e0] * inv, p1 = p[e1] * inv;
    float rn = 1.f / (p0 + p1);
    tki[2 * t] = e0; tki[2 * t + 1] = e1;
    tkp[2 * t] = p0 * rn; tkp[2 * t + 1] = p1 * rn;
    float4 pa = {p[0] * inv, p[1] * inv, p[2] * inv, p[3] * inv};
    float4 pb = {p[4] * inv, p[5] * inv, p[6] * inv, p[7] * inv};
    ((float4*)(probs + t * 8))[0] = pa;
    ((float4*)(probs + t * 8))[1] = pb;
    float lse = __logf(s) + m;
    lse2[t] = lse * lse;
  }
}

// ---------------- rankred: block0 = rank+dispatch; blocks 1..8 = router stats; blocks 9+ = wo cast ----------------
__global__ __launch_bounds__(1024) void rankred_kernel(
    const int* __restrict__ tki, const float* __restrict__ tkp,
    const float* __restrict__ probs, const float* __restrict__ lse2,
    int* __restrict__ ltk, float* __restrict__ lw,
    int* __restrict__ counts, int* __restrict__ baserow, int* __restrict__ kflags,
    int* __restrict__ fcnt, float* __restrict__ psum, float* __restrict__ zsum,
    const float* __restrict__ wo, u16* __restrict__ wob) {
  int bid = blockIdx.x;
  int tid = threadIdx.x;
  if (bid >= 9) {
    // ---- wo cast on idle CUs (hides behind serial block-0 dispatch scan) ----
    int j = (bid - 9) * 1024 + tid;
    cast8(wo, wob, j);
    return;
  }
  if (bid >= 1) {
    // ---- router stats reduce ----
    int t = (bid - 1) * 1024 + tid;
    float4 pa = ((const float4*)(probs + t * 8))[0];
    float4 pb = ((const float4*)(probs + t * 8))[1];
    float p[8] = {pa.x, pa.y, pa.z, pa.w, pb.x, pb.y, pb.z, pb.w};
    float z = lse2[t];
    int e0 = tki[2 * t], e1 = tki[2 * t + 1];
    int fc[8];
#pragma unroll
    for (int e = 0; e < 8; e++) fc[e] = (e0 == e ? 1 : 0) + (e1 == e ? 1 : 0);
#pragma unroll
    for (int off = 32; off > 0; off >>= 1) {
#pragma unroll
      for (int e = 0; e < 8; e++) { p[e] += __shfl_xor(p[e], off); fc[e] += __shfl_xor(fc[e], off); }
      z += __shfl_xor(z, off);
    }
    __shared__ float sp[16][9];
    __shared__ int sf[16][8];
    int wv = tid >> 6, lane = tid & 63;
    if (lane == 0) {
#pragma unroll
      for (int e = 0; e < 8; e++) { sp[wv][e] = p[e]; sf[wv][e] = fc[e]; }
      sp[wv][8] = z;
    }
    __syncthreads();
    if (tid < 9) {
      float s = 0.f;
      for (int w = 0; w < 16; w++) s += sp[w][tid];
      if (tid < 8) atomicAdd(&psum[tid], s);
      else atomicAdd(zsum, s);
    }
    if (tid >= 64 && tid < 72) {
      int e = tid - 64;
      int s = 0;
      for (int w = 0; w < 16; w++) s += sf[w][e];
      atomicAdd(&fcnt[e], s);
    }
    return;
  }
  // ---- block 0: rank + dispatch (deterministic, no atomics) ----
  __shared__ int wave_cnt[2][16][8];
  __shared__ int base[2][8];
  __shared__ int sc0[8];
  int wv = tid >> 6, lane = tid & 63;
  int c0w[8];
#pragma unroll
  for (int e = 0; e < 8; e++) c0w[e] = 0;
  for (int c = 0; c < T_TOK / 1024; c++) {
    int e0 = tki[2 * (c * 1024 + tid)];
#pragma unroll
    for (int e = 0; e < 8; e++) {
      u64 m = __ballot(e0 == e);
      if (lane == 0) c0w[e] += __popcll(m);
    }
  }
  if (lane == 0) {
#pragma unroll
    for (int e = 0; e < 8; e++) wave_cnt[0][wv][e] = c0w[e];
  }
  if (tid < 16) base[tid >> 3][tid & 7] = 0;
  __syncthreads();
  if (tid < 8) {
    int s = 0;
    for (int w = 0; w < 16; w++) s += wave_cnt[0][w][tid];
    sc0[tid] = (s < CAP) ? s : CAP;
  }
  __syncthreads();
  u64 lmask = (lane == 63) ? 0x7FFFFFFFFFFFFFFFull : ((1ull << lane) - 1ull);
  for (int c = 0; c < T_TOK / 1024; c++) {
    int t = c * 1024 + tid;
    int e0 = tki[2 * t], e1 = tki[2 * t + 1];
    float p0 = tkp[2 * t], p1 = tkp[2 * t + 1];
    int pre0 = 0, pre1 = 0;
    for (int e = 0; e < 8; e++) {
      u64 m0 = __ballot(e0 == e);
      if (e0 == e) pre0 = __popcll(m0 & lmask);
      if (lane == 0) wave_cnt[0][wv][e] = __popcll(m0);
      u64 m1 = __ballot(e1 == e);
      if (e1 == e) pre1 = __popcll(m1 & lmask);
      if (lane == 0) wave_cnt[1][wv][e] = __popcll(m1);
    }
    __syncthreads();
    if (tid < 16) {
      int k = tid >> 3, e = tid & 7;
      int run = base[k][e];
      for (int w = 0; w < 16; w++) {
        int v = wave_cnt[k][w][e];
        wave_cnt[k][w][e] = run;
        run += v;
      }
      base[k][e] = run;
    }
    __syncthreads();
    int r0 = wave_cnt[0][wv][e0] + pre0;
    int r1 = wave_cnt[1][wv][e1] + pre1;
    if (r0 < CAP) { ltk[e0 * LSTR + r0] = (t << 1); lw[e0 * LSTR + r0] = p0; }
    if (r1 < CAP) {
      int p = sc0[e1] + r1;
      ltk[e1 * LSTR + p] = (t << 1) | 1; lw[e1 * LSTR + p] = p1;
    }
    kflags[t] = (r0 < CAP ? 1 : 0) | (r1 < CAP ? 2 : 0);
    __syncthreads();
  }
  if (tid == 0) {
    int run = 0;
    for (int e = 0; e < 8; e++) {
      int c1 = base[1][e]; if (c1 > CAP) c1 = CAP;
      int cnt = sc0[e] + c1;
      counts[e] = cnt; baserow[e] = run; run += cnt;
    }
  }
}

// ---------------- GEMM1: H = silu(x@Wg^T) * (x@Wu^T), tile 128x64, BK=64, XOR-swizzled LDS ----------------
__global__ __launch_bounds__(256, 2) void gemm1_kernel(
    const u16* __restrict__ xb, const u16* __restrict__ wgb, const u16* __restrict__ wub,
    u16* __restrict__ H, const int* __restrict__ counts, const int* __restrict__ baserow,
    const int* __restrict__ ltk) {
  // swizzle: groups g=(e*48+nt) share weights; members mt on same XCD
  int id = blockIdx.x;
  int xcd = id & 7;
  int q = id >> 3;          // [0, 960)
  int gg = q / MAXMT;       // [0, 48)
  int mt = q - gg * MAXMT;  // [0, 20)
  int g = gg * 8 + xcd;     // [0, 384)
  int e = g / 48;
  int nt = g - e * 48;      // [0, 48)
  int cnt = counts[e];
  if (mt * 128 >= cnt) return;

  __shared__ u16 As[128 * 64];
  __shared__ u16 Bg[64 * 64];
  __shared__ u16 Bu[64 * 64];
  __shared__ int toks[128];
  int tid = threadIdx.x;
  if (tid < 128) {
    int r = mt * 128 + tid; if (r > cnt - 1) r = cnt - 1;
    toks[tid] = ltk[e * LSTR + r] >> 1;
  }
  __syncthreads();
  // staging: each thread loads 16B; row = tid>>3 (32 rows/call), slot = tid&7.
  // LDS dest LINEAR (global_load_lds constraint); global SOURCE inverse-swizzled.
  int rq8 = tid >> 3;                     // [0,32)
  int swz = ((tid & 7) ^ (rq8 & 7)) * 8;  // swizzled 8xu16 chunk within 64-col row
  long tA0 = toks[rq8], tA1 = toks[32 + rq8], tA2 = toks[64 + rq8], tA3 = toks[96 + rq8];
  const u16* gA0 = xb + tA0 * DIM + swz;
  const u16* gA1 = xb + tA1 * DIM + swz;
  const u16* gA2 = xb + tA2 * DIM + swz;
  const u16* gA3 = xb + tA3 * DIM + swz;
  long bO0 = ((long)e * FF + nt * 64 + rq8) * DIM + swz;
  long bO1 = bO0 + 32l * DIM;
  const u16* gG0 = wgb + bO0; const u16* gG1 = wgb + bO1;
  const u16* gU0 = wub + bO0; const u16* gU1 = wub + bO1;
  u16* dA0 = As + tid * 8; u16* dA1 = dA0 + 2048; u16* dA2 = dA0 + 4096; u16* dA3 = dA0 + 6144;
  u16* dG0 = Bg + tid * 8; u16* dG1 = dG0 + 2048;
  u16* dU0 = Bu + tid * 8; u16* dU1 = dU0 + 2048;

  int lane = tid & 63, wv = tid >> 6;
  int wm = (wv & 1) * 64, wn = (wv >> 1) * 32;
  int lrow = lane & 15, quad = lane >> 4;
  // read-side swizzle: logical slot (quad + kk*4) ^ (row&7); row&7 == lrow&7
  int sl0 = (quad ^ (lrow & 7)) * 8;
  int sl1 = ((quad + 4) ^ (lrow & 7)) * 8;

  f4v zero = {0.f, 0.f, 0.f, 0.f};
  f4v accg[4][2], accu[4][2];
#pragma unroll
  for (int i = 0; i < 4; i++)
#pragma unroll
    for (int j = 0; j < 2; j++) { accg[i][j] = zero; accu[i][j] = zero; }

  for (int kt = 0; kt < DIM / 64; kt++) {
    int ko = kt * 64;
    __syncthreads();
    glds16(gA0 + ko, dA0); glds16(gA1 + ko, dA1);
    glds16(gA2 + ko, dA2); glds16(gA3 + ko, dA3);
    glds16(gG0 + ko, dG0); glds16(gG1 + ko, dG1);
    glds16(gU0 + ko, dU0); glds16(gU1 + ko, dU1);
    __syncthreads();
#pragma unroll
    for (int kk = 0; kk < 2; kk++) {
      int sl = kk ? sl1 : sl0;
      s8v a[4], bgf[2], buf[2];
#pragma unroll
      for (int i = 0; i < 4; i++)
        a[i] = *(const s8v*)&As[(wm + i * 16 + lrow) * 64 + sl];
#pragma unroll
      for (int j = 0; j < 2; j++) {
        bgf[j] = *(const s8v*)&Bg[(wn + j * 16 + lrow) * 64 + sl];
        buf[j] = *(const s8v*)&Bu[(wn + j * 16 + lrow) * 64 + sl];
      }
#pragma unroll
      for (int i = 0; i < 4; i++)
#pragma unroll
        for (int j = 0; j < 2; j++) {
          accg[i][j] = __builtin_amdgcn_mfma_f32_16x16x32_bf16(a[i], bgf[j], accg[i][j], 0, 0, 0);
          accu[i][j] = __builtin_amdgcn_mfma_f32_16x16x32_bf16(a[i], buf[j], accu[i][j], 0, 0, 0);
        }
    }
  }
  long hb = (long)baserow[e] + (long)mt * 128;
#pragma unroll
  for (int i = 0; i < 4; i++) {
#pragma unroll
    for (int r = 0; r < 4; r++) {
      int m = wm + i * 16 + quad * 4 + r;
      if (mt * 128 + m < cnt) {
#pragma unroll
        for (int j = 0; j < 2; j++) {
          float gv = accg[i][j][r], uv = accu[i][j][r];
          float h = gv / (1.f + __expf(-gv)) * uv;
          H[(hb + m) * FF + nt * 64 + wn + j * 16 + lrow] = f2bf(h);
        }
      }
    }
  }
}

// ---------------- GEMM2: ybuf[(t,k)] = (H @ wo^T) * w, plain stores (no atomics) ----------------
__global__ __launch_bounds__(256, 2) void gemm2_kernel(
    const u16* __restrict__ H, const u16* __restrict__ wob,
    float* __restrict__ ybuf, const int* __restrict__ counts, const int* __restrict__ baserow,
    const int* __restrict__ ltk, const float* __restrict__ lw) {
  // swizzle: groups g=(e*20+mt) share H rows; members nt on same XCD
  int id = blockIdx.x;
  int xcd = id & 7;
  int q = id >> 3;        // [0, 120)
  int gg = q / 6;         // [0, 20)
  int nt = q - gg * 6;    // [0, 6)
  int g = gg * 8 + xcd;   // [0, 160)
  int e = g / MAXMT;
  int mt = g - e * MAXMT;
  int cnt = counts[e];
  if (mt * 128 >= cnt) return;

  __shared__ u16 As[128 * 64];
  __shared__ u16 Bs[128 * 64];
  __shared__ int stok[128];
  __shared__ float sw[128];
  int tid = threadIdx.x;
  if (tid < 128) {
    int r = mt * 128 + tid; if (r > cnt - 1) r = cnt - 1;
    stok[tid] = ltk[e * LSTR + r];
    sw[tid] = lw[e * LSTR + r];
  }
  long hb = (long)baserow[e] + (long)mt * 128;
  int rq8 = tid >> 3;
  int swz = ((tid & 7) ^ (rq8 & 7)) * 8;
  const u16* gA0 = H + (hb + rq8) * FF + swz;
  const u16* gA1 = gA0 + 32l * FF;
  const u16* gA2 = gA0 + 64l * FF;
  const u16* gA3 = gA0 + 96l * FF;
  long bOff = ((long)e * DIM + nt * 128 + rq8) * FF + swz;
  const u16* gB0 = wob + bOff;
  const u16* gB1 = gB0 + 32l * FF;
  const u16* gB2 = gB0 + 64l * FF;
  const u16* gB3 = gB0 + 96l * FF;
  u16* dA0 = As + tid * 8; u16* dA1 = dA0 + 2048; u16* dA2 = dA0 + 4096; u16* dA3 = dA0 + 6144;
  u16* dB0 = Bs + tid * 8; u16* dB1 = dB0 + 2048; u16* dB2 = dB0 + 4096; u16* dB3 = dB0 + 6144;
  int lane = tid & 63, wv = tid >> 6;
  int wm = (wv & 1) * 64, wn = (wv >> 1) * 64;
  int lrow = lane & 15, quad = lane >> 4;
  int sl0 = (quad ^ (lrow & 7)) * 8;
  int sl1 = ((quad + 4) ^ (lrow & 7)) * 8;
  f4v zero = {0.f, 0.f, 0.f, 0.f};
  f4v acc[4][4];
#pragma unroll
  for (int i = 0; i < 4; i++)
#pragma unroll
    for (int j = 0; j < 4; j++) acc[i][j] = zero;

  for (int kt = 0; kt < FF / 64; kt++) {
    int ko = kt * 64;
    __syncthreads();
    glds16(gA0 + ko, dA0); glds16(gA1 + ko, dA1);
    glds16(gA2 + ko, dA2); glds16(gA3 + ko, dA3);
    glds16(gB0 + ko, dB0); glds16(gB1 + ko, dB1);
    glds16(gB2 + ko, dB2); glds16(gB3 + ko, dB3);
    __syncthreads();
#pragma unroll
    for (int kk = 0; kk < 2; kk++) {
      int sl = kk ? sl1 : sl0;
      s8v a[4], b[4];
#pragma unroll
      for (int i = 0; i < 4; i++)
        a[i] = *(const s8v*)&As[(wm + i * 16 + lrow) * 64 + sl];
#pragma unroll
      for (int j = 0; j < 4; j++)
        b[j] = *(const s8v*)&Bs[(wn + j * 16 + lrow) * 64 + sl];
#pragma unroll
      for (int i = 0; i < 4; i++)
#pragma unroll
        for (int j = 0; j < 4; j++)
          acc[i][j] = __builtin_amdgcn_mfma_f32_16x16x32_bf16(a[i], b[j], acc[i][j], 0, 0, 0);
    }
  }
#pragma unroll
  for (int i = 0; i < 4; i++) {
#pragma unroll
    for (int r = 0; r < 4; r++) {
      int m = wm + i * 16 + quad * 4 + r;
      if (mt * 128 + m < cnt) {
        int entry = stok[m];       // (t<<1)|k  == ybuf row index
        float w = sw[m];
        long ob = (long)entry * DIM + nt * 128;
#pragma unroll
        for (int j = 0; j < 4; j++)
          ybuf[ob + wn + j * 16 + lrow] = acc[i][j][r] * w;
      }
    }
  }
}

// ---------------- combine + aux: out[t] = sum of kept (t,k) contributions; last block = aux ----------------
__global__ __launch_bounds__(256) void combine_aux_kernel(
    const float* __restrict__ ybuf, const int* __restrict__ kflags, float* __restrict__ out,
    const int* __restrict__ fcnt, const float* __restrict__ psum, const float* __restrict__ zsum) {
  int bid = blockIdx.x;
  if (bid == T_TOK * DIM / 4 / 256) {
    if (threadIdx.x == 0) {
      float lb = 0.f;
      for (int e = 0; e < 8; e++)
        lb += ((float)fcnt[e] / (float)(T_TOK * 2)) * (psum[e] / (float)T_TOK);
      lb *= 8.f;
      float z = zsum[0] / (float)T_TOK;
      out[(size_t)T_TOK * DIM] = 0.01f * lb + 0.001f * z;
    }
    return;
  }
  int idx = bid * 256 + threadIdx.x;   // [0, T*DIM/4)
  int t = idx / (DIM / 4);
  int d4 = idx - t * (DIM / 4);
  int kf = kflags[t];
  float4 r = {0.f, 0.f, 0.f, 0.f};
  if (kf & 1) {
    float4 a = ((const float4*)(ybuf + (long)(2 * t) * DIM))[d4];
    r.x += a.x; r.y += a.y; r.z += a.z; r.w += a.w;
  }
  if (kf & 2) {
    float4 b = ((const float4*)(ybuf + (long)(2 * t + 1) * DIM))[d4];
    r.x += b.x; r.y += b.y; r.z += b.z; r.w += b.w;
  }
  ((float4*)out)[idx] = r;
}

extern "C" void kernel_launch(void* const* d_in, const int* in_sizes, int n_in,
                              void* d_out, int out_size, void* d_ws, size_t ws_size,
                              hipStream_t stream) {
  const float* x = (const float*)d_in[0];
  const float* wgate = (const float*)d_in[1];
  const float* wig = (const float*)d_in[2];
  const float* wiu = (const float*)d_in[3];
  const float* wo = (const float*)d_in[4];
  float* out = (float*)d_out;

  char* ws = (char*)d_ws;
  size_t off = 0;
  auto alloc = [&](size_t bytes) {
    void* p = ws + off;
    off += (bytes + 255) & ~(size_t)255;
    return p;
  };
  int* ctrl = (int*)alloc(256);
  u16* xb = (u16*)alloc((size_t)T_TOK * DIM * 2);
  u16* wgb = (u16*)alloc((size_t)NE * FF * DIM * 2);
  u16* wub = (u16*)alloc((size_t)NE * FF * DIM * 2);
  u16* wob = (u16*)alloc((size_t)NE * DIM * FF * 2);
  u16* Hbuf = (u16*)alloc((size_t)(T_TOK * 2 + 128) * FF * 2);
  int* tki = (int*)alloc((size_t)T_TOK * 2 * 4);
  float* tkp = (float*)alloc((size_t)T_TOK * 2 * 4);
  int* ltk = (int*)alloc((size_t)NE * LSTR * 4);
  float* lw = (float*)alloc((size_t)NE * LSTR * 4);
  float* probs = (float*)alloc((size_t)T_TOK * 8 * 4);
  float* lse2 = (float*)alloc((size_t)T_TOK * 4);
  int* kflags = (int*)alloc((size_t)T_TOK * 4);
  // ybuf [T*2, DIM] fp32 (50.3MB) aliases wgb+wub (75.5MB): weights dead after gemm1
  float* ybuf = (float*)wgb;

  int* fcnt = ctrl;
  int* counts = ctrl + 8;
  int* baserow = ctrl + 16;
  float* psum = (float*)(ctrl + 24);
  float* zsum = (float*)(ctrl + 32);

  pre_kernel<<<NCAST2 + T_TOK / 4, 256, 0, stream>>>(
      wig, wiu, wgb, wub, x, wgate, xb, tki, tkp, probs, lse2, ctrl);
  rankred_kernel<<<9 + NWOCAST, 1024, 0, stream>>>(
      tki, tkp, probs, lse2, ltk, lw, counts, baserow, kflags, fcnt, psum, zsum, wo, wob);
  gemm1_kernel<<<8 * 48 * MAXMT, 256, 0, stream>>>(xb, wgb, wub, Hbuf, counts, baserow, ltk);
  gemm2_kernel<<<8 * MAXMT * 6, 256, 0, stream>>>(Hbuf, wob, ybuf, counts, baserow, ltk, lw);
  combine_aux_kernel<<<T_TOK * DIM / 4 / 256 + 1, 256, 0, stream>>>(
      ybuf, kflags, out, fcnt, psum, zsum);
}

// Round 9
// 546.029 us; speedup vs baseline: 1.1473x; 1.0104x over previous
//
#include <hip/hip_runtime.h>

typedef unsigned short u16;
typedef unsigned int u32;
typedef unsigned long long u64;

#define T_TOK 8192
#define DIM 768
#define FF 3072
#define NE 8
#define CAP 2560
#define LSTR 5120
#define MAXMT 20
#define N8EACH 2359296          // NE*FF*DIM/8
#define NCAST2 18432            // 2*N8EACH/256 (wig+wiu cast blocks in pre)
#define G1BLK 7680              // 8*48*20 gemm1 tile blocks
#define NWOCAST 2304            // N8EACH/1024 wo-cast blocks appended to gemm1 grid

typedef __attribute__((ext_vector_type(8))) short s8v;
typedef __attribute__((ext_vector_type(4))) float f4v;

__device__ __forceinline__ u16 f2bf(float f) {
  union { float f; u32 u; } v; v.f = f;
  u32 r = v.u + 0x7FFFu + ((v.u >> 16) & 1u);
  return (u16)(r >> 16);
}

__device__ __forceinline__ void glds16(const void* g, void* l) {
  __builtin_amdgcn_global_load_lds(
      (const __attribute__((address_space(1))) u32*)g,
      (__attribute__((address_space(3))) u32*)l, 16, 0, 0);
}

__device__ __forceinline__ void cast8(const float* __restrict__ s, u16* __restrict__ d, int j) {
  const float4* s4 = (const float4*)s;
  float4 a = s4[2 * j], b = s4[2 * j + 1];
  uint4 o;
  o.x = (u32)f2bf(a.x) | ((u32)f2bf(a.y) << 16);
  o.y = (u32)f2bf(a.z) | ((u32)f2bf(a.w) << 16);
  o.z = (u32)f2bf(b.x) | ((u32)f2bf(b.y) << 16);
  o.w = (u32)f2bf(b.z) | ((u32)f2bf(b.w) << 16);
  ((uint4*)d)[j] = o;
}

// ctrl layout (ints): [0..7]=fcnt  [8..15]=cnt0(capped)  [16..23]=cnt1(capped)
//                     [24..31]=psum(float)  [32]=zsum(float)

// ---------------- pre: wig/wiu casts (blocks 0..NCAST2-1) + router (rest); zeroes ctrl ----------------
__global__ __launch_bounds__(256) void pre_kernel(
    const float* __restrict__ wig, const float* __restrict__ wiu,
    u16* __restrict__ wgb, u16* __restrict__ wub,
    const float* __restrict__ x, const float* __restrict__ wg, u16* __restrict__ xb,
    int* __restrict__ tki, float* __restrict__ tkp,
    float* __restrict__ probs, float* __restrict__ lse2, int* __restrict__ ctrl) {
  int bid = blockIdx.x;
  if (bid == 0 && threadIdx.x < 64) ctrl[threadIdx.x] = 0;
  if (bid < NCAST2) {
    int i = bid * 256 + threadIdx.x;
    if (i < N8EACH) cast8(wig, wgb, i);
    else cast8(wiu, wub, i - N8EACH);
    return;
  }
  int rb = bid - NCAST2;
  int lane = threadIdx.x & 63;
  int t = rb * 4 + (threadIdx.x >> 6);
  const float* xr = x + (long)t * DIM;
  u16* xw = xb + (long)t * DIM;
  float acc[NE];
#pragma unroll
  for (int e = 0; e < NE; e++) acc[e] = 0.f;
  for (int i = 0; i < DIM / 64; i++) {
    float xv = xr[lane + 64 * i];
    xw[lane + 64 * i] = f2bf(xv);
#pragma unroll
    for (int e = 0; e < NE; e++) acc[e] += xv * wg[e * DIM + lane + 64 * i];
  }
#pragma unroll
  for (int off = 32; off > 0; off >>= 1) {
#pragma unroll
    for (int e = 0; e < NE; e++) acc[e] += __shfl_xor(acc[e], off);
  }
  if (lane == 0) {
    float m = acc[0];
#pragma unroll
    for (int e = 1; e < NE; e++) m = fmaxf(m, acc[e]);
    float p[NE], s = 0.f;
#pragma unroll
    for (int e = 0; e < NE; e++) { p[e] = __expf(acc[e] - m); s += p[e]; }
    float inv = 1.f / s;
    int e0 = 0;
#pragma unroll
    for (int e = 1; e < NE; e++) if (acc[e] > acc[e0]) e0 = e;
    int e1 = (e0 == 0) ? 1 : 0;
#pragma unroll
    for (int e = 0; e < NE; e++) if (e != e0 && acc[e] > acc[e1]) e1 = e;
    float p0 = p[e0] * inv, p1 = p[e1] * inv;
    float rn = 1.f / (p0 + p1);
    tki[2 * t] = e0; tki[2 * t + 1] = e1;
    tkp[2 * t] = p0 * rn; tkp[2 * t + 1] = p1 * rn;
    float4 pa = {p[0] * inv, p[1] * inv, p[2] * inv, p[3] * inv};
    float4 pb = {p[4] * inv, p[5] * inv, p[6] * inv, p[7] * inv};
    ((float4*)(probs + t * 8))[0] = pa;
    ((float4*)(probs + t * 8))[1] = pb;
    float lse = __logf(s) + m;
    lse2[t] = lse * lse;
  }
}

// ---------------- rankred: blocks 0..15 = per-(e,k) rank; blocks 16..23 = router stats ----------------
__global__ __launch_bounds__(1024) void rankred_kernel(
    const int* __restrict__ tki, const float* __restrict__ tkp,
    const float* __restrict__ probs, const float* __restrict__ lse2,
    int* __restrict__ ltk, float* __restrict__ lw, int* __restrict__ ctrl,
    int* __restrict__ kflags0, int* __restrict__ kflags1) {
  int bid = blockIdx.x;
  int tid = threadIdx.x;
  int wv = tid >> 6, lane = tid & 63;
  if (bid >= 16) {
    // ---- router stats reduce ----
    int t = (bid - 16) * 1024 + tid;
    float4 pa = ((const float4*)(probs + t * 8))[0];
    float4 pb = ((const float4*)(probs + t * 8))[1];
    float p[8] = {pa.x, pa.y, pa.z, pa.w, pb.x, pb.y, pb.z, pb.w};
    float z = lse2[t];
    int e0 = tki[2 * t], e1 = tki[2 * t + 1];
    int fc[8];
#pragma unroll
    for (int e = 0; e < 8; e++) fc[e] = (e0 == e ? 1 : 0) + (e1 == e ? 1 : 0);
#pragma unroll
    for (int off = 32; off > 0; off >>= 1) {
#pragma unroll
      for (int e = 0; e < 8; e++) { p[e] += __shfl_xor(p[e], off); fc[e] += __shfl_xor(fc[e], off); }
      z += __shfl_xor(z, off);
    }
    __shared__ float sp[16][9];
    __shared__ int sf[16][8];
    if (lane == 0) {
#pragma unroll
      for (int e = 0; e < 8; e++) { sp[wv][e] = p[e]; sf[wv][e] = fc[e]; }
      sp[wv][8] = z;
    }
    __syncthreads();
    float* psum = (float*)(ctrl + 24);
    float* zsum = (float*)(ctrl + 32);
    if (tid < 9) {
      float s = 0.f;
      for (int w = 0; w < 16; w++) s += sp[w][tid];
      if (tid < 8) atomicAdd(&psum[tid], s);
      else atomicAdd(zsum, s);
    }
    if (tid >= 64 && tid < 72) {
      int e = tid - 64;
      int s = 0;
      for (int w = 0; w < 16; w++) s += sf[w][e];
      atomicAdd(&ctrl[e], s);
    }
    return;
  }
  // ---- rank block for (e, k): independent prefix-count over token order ----
  int k = bid & 1, e = bid >> 1;
  __shared__ int wcnt[16];
  __shared__ int runbase;
  __shared__ int s_sc0;
  u64 lmask = (lane == 63) ? 0x7FFFFFFFFFFFFFFFull : ((1ull << lane) - 1ull);
  int sc0 = 0;
  if (k == 1) {
    // total top-1 count for e (determines k=1 list base)
    int c0 = 0;
    for (int c = 0; c < T_TOK / 1024; c++) {
      int e0 = tki[2 * (c * 1024 + tid)];
      u64 m = __ballot(e0 == e);
      if (lane == 0) c0 += __popcll(m);
    }
    if (lane == 0) wcnt[wv] = c0;
    __syncthreads();
    if (tid == 0) {
      int s = 0;
      for (int w = 0; w < 16; w++) s += wcnt[w];
      s_sc0 = (s < CAP) ? s : CAP;
    }
    __syncthreads();
    sc0 = s_sc0;
  }
  if (tid == 0) runbase = 0;
  __syncthreads();
  for (int c = 0; c < T_TOK / 1024; c++) {
    int t = c * 1024 + tid;
    int ek = tki[2 * t + k];
    float pk = tkp[2 * t + k];
    u64 m = __ballot(ek == e);
    int pre = __popcll(m & lmask);
    if (lane == 0) wcnt[wv] = __popcll(m);
    __syncthreads();
    int waveoff = runbase;
    for (int w = 0; w < wv; w++) waveoff += wcnt[w];
    int r = waveoff + pre;
    if (ek == e) {
      int keep = (r < CAP) ? 1 : 0;
      if (keep) {
        int p = sc0 + r;
        ltk[e * LSTR + p] = (t << 1) | k;
        lw[e * LSTR + p] = pk;
      }
      if (k == 0) kflags0[t] = keep; else kflags1[t] = keep;
    }
    __syncthreads();
    if (tid == 0) {
      int tot = 0;
      for (int w = 0; w < 16; w++) tot += wcnt[w];
      runbase += tot;
    }
    __syncthreads();
  }
  if (tid == 0) {
    int cnt = runbase; if (cnt > CAP) cnt = CAP;
    ctrl[8 + k * 8 + e] = cnt;
  }
}

// per-block derive of expert count + H-row base from ctrl (cnt0+cnt1, prefix sum)
__device__ __forceinline__ void expert_extent(const int* __restrict__ ctrl, int e,
                                              int& cnt, long& hb0) {
  cnt = 0; hb0 = 0;
#pragma unroll
  for (int i = 0; i < 8; i++) {
    int ci = ctrl[8 + i] + ctrl[16 + i];
    if (i < e) hb0 += ci;
    if (i == e) cnt = ci;
  }
}

// ---------------- GEMM1: tile blocks [0,G1BLK) + wo-cast tail blocks ----------------
__global__ __launch_bounds__(256, 2) void gemm1_kernel(
    const u16* __restrict__ xb, const u16* __restrict__ wgb, const u16* __restrict__ wub,
    u16* __restrict__ H, const int* __restrict__ ctrl, const int* __restrict__ ltk,
    const float* __restrict__ wo, u16* __restrict__ wob) {
  int id = blockIdx.x;
  if (id >= G1BLK) {
    // wo cast riding in gemm1's shadow (gemm1 is latency-bound, HBM at ~22%)
    int base = (id - G1BLK) * 1024 + threadIdx.x;
#pragma unroll
    for (int c = 0; c < 4; c++) cast8(wo, wob, base + c * 256);
    return;
  }
  // swizzle: groups g=(e*48+nt) share weights; members mt on same XCD
  int xcd = id & 7;
  int q = id >> 3;          // [0, 960)
  int gg = q / MAXMT;       // [0, 48)
  int mt = q - gg * MAXMT;  // [0, 20)
  int g = gg * 8 + xcd;     // [0, 384)
  int e = g / 48;
  int nt = g - e * 48;      // [0, 48)
  int cnt; long hb0;
  expert_extent(ctrl, e, cnt, hb0);
  if (mt * 128 >= cnt) return;

  __shared__ u16 As[128 * 64];
  __shared__ u16 Bg[64 * 64];
  __shared__ u16 Bu[64 * 64];
  __shared__ int toks[128];
  int tid = threadIdx.x;
  if (tid < 128) {
    int r = mt * 128 + tid; if (r > cnt - 1) r = cnt - 1;
    toks[tid] = ltk[e * LSTR + r] >> 1;
  }
  __syncthreads();
  int rq8 = tid >> 3;                     // [0,32)
  int swz = ((tid & 7) ^ (rq8 & 7)) * 8;  // swizzled 8xu16 chunk within 64-col row
  long tA0 = toks[rq8], tA1 = toks[32 + rq8], tA2 = toks[64 + rq8], tA3 = toks[96 + rq8];
  const u16* gA0 = xb + tA0 * DIM + swz;
  const u16* gA1 = xb + tA1 * DIM + swz;
  const u16* gA2 = xb + tA2 * DIM + swz;
  const u16* gA3 = xb + tA3 * DIM + swz;
  long bO0 = ((long)e * FF + nt * 64 + rq8) * DIM + swz;
  long bO1 = bO0 + 32l * DIM;
  const u16* gG0 = wgb + bO0; const u16* gG1 = wgb + bO1;
  const u16* gU0 = wub + bO0; const u16* gU1 = wub + bO1;
  u16* dA0 = As + tid * 8; u16* dA1 = dA0 + 2048; u16* dA2 = dA0 + 4096; u16* dA3 = dA0 + 6144;
  u16* dG0 = Bg + tid * 8; u16* dG1 = dG0 + 2048;
  u16* dU0 = Bu + tid * 8; u16* dU1 = dU0 + 2048;

  int lane = tid & 63, wv = tid >> 6;
  int wm = (wv & 1) * 64, wn = (wv >> 1) * 32;
  int lrow = lane & 15, quad = lane >> 4;
  int sl0 = (quad ^ (lrow & 7)) * 8;
  int sl1 = ((quad + 4) ^ (lrow & 7)) * 8;

  f4v zero = {0.f, 0.f, 0.f, 0.f};
  f4v accg[4][2], accu[4][2];
#pragma unroll
  for (int i = 0; i < 4; i++)
#pragma unroll
    for (int j = 0; j < 2; j++) { accg[i][j] = zero; accu[i][j] = zero; }

  for (int kt = 0; kt < DIM / 64; kt++) {
    int ko = kt * 64;
    __syncthreads();
    glds16(gA0 + ko, dA0); glds16(gA1 + ko, dA1);
    glds16(gA2 + ko, dA2); glds16(gA3 + ko, dA3);
    glds16(gG0 + ko, dG0); glds16(gG1 + ko, dG1);
    glds16(gU0 + ko, dU0); glds16(gU1 + ko, dU1);
    __syncthreads();
#pragma unroll
    for (int kk = 0; kk < 2; kk++) {
      int sl = kk ? sl1 : sl0;
      s8v a[4], bgf[2], buf[2];
#pragma unroll
      for (int i = 0; i < 4; i++)
        a[i] = *(const s8v*)&As[(wm + i * 16 + lrow) * 64 + sl];
#pragma unroll
      for (int j = 0; j < 2; j++) {
        bgf[j] = *(const s8v*)&Bg[(wn + j * 16 + lrow) * 64 + sl];
        buf[j] = *(const s8v*)&Bu[(wn + j * 16 + lrow) * 64 + sl];
      }
#pragma unroll
      for (int i = 0; i < 4; i++)
#pragma unroll
        for (int j = 0; j < 2; j++) {
          accg[i][j] = __builtin_amdgcn_mfma_f32_16x16x32_bf16(a[i], bgf[j], accg[i][j], 0, 0, 0);
          accu[i][j] = __builtin_amdgcn_mfma_f32_16x16x32_bf16(a[i], buf[j], accu[i][j], 0, 0, 0);
        }
    }
  }
  long hb = hb0 + (long)mt * 128;
#pragma unroll
  for (int i = 0; i < 4; i++) {
#pragma unroll
    for (int r = 0; r < 4; r++) {
      int m = wm + i * 16 + quad * 4 + r;
      if (mt * 128 + m < cnt) {
#pragma unroll
        for (int j = 0; j < 2; j++) {
          float gv = accg[i][j][r], uv = accu[i][j][r];
          float h = gv / (1.f + __expf(-gv)) * uv;
          H[(hb + m) * FF + nt * 64 + wn + j * 16 + lrow] = f2bf(h);
        }
      }
    }
  }
}

// ---------------- GEMM2: ybuf[(t,k)] = (H @ wo^T) * w, plain stores (no atomics) ----------------
__global__ __launch_bounds__(256, 2) void gemm2_kernel(
    const u16* __restrict__ H, const u16* __restrict__ wob,
    float* __restrict__ ybuf, const int* __restrict__ ctrl,
    const int* __restrict__ ltk, const float* __restrict__ lw) {
  // swizzle: groups g=(e*20+mt) share H rows; members nt on same XCD
  int id = blockIdx.x;
  int xcd = id & 7;
  int q = id >> 3;        // [0, 120)
  int gg = q / 6;         // [0, 20)
  int nt = q - gg * 6;    // [0, 6)
  int g = gg * 8 + xcd;   // [0, 160)
  int e = g / MAXMT;
  int mt = g - e * MAXMT;
  int cnt; long hb0;
  expert_extent(ctrl, e, cnt, hb0);
  if (mt * 128 >= cnt) return;

  __shared__ u16 As[128 * 64];
  __shared__ u16 Bs[128 * 64];
  __shared__ int stok[128];
  __shared__ float sw[128];
  int tid = threadIdx.x;
  if (tid < 128) {
    int r = mt * 128 + tid; if (r > cnt - 1) r = cnt - 1;
    stok[tid] = ltk[e * LSTR + r];
    sw[tid] = lw[e * LSTR + r];
  }
  long hb = hb0 + (long)mt * 128;
  int rq8 = tid >> 3;
  int swz = ((tid & 7) ^ (rq8 & 7)) * 8;
  const u16* gA0 = H + (hb + rq8) * FF + swz;
  const u16* gA1 = gA0 + 32l * FF;
  const u16* gA2 = gA0 + 64l * FF;
  const u16* gA3 = gA0 + 96l * FF;
  long bOff = ((long)e * DIM + nt * 128 + rq8) * FF + swz;
  const u16* gB0 = wob + bOff;
  const u16* gB1 = gB0 + 32l * FF;
  const u16* gB2 = gB0 + 64l * FF;
  const u16* gB3 = gB0 + 96l * FF;
  u16* dA0 = As + tid * 8; u16* dA1 = dA0 + 2048; u16* dA2 = dA0 + 4096; u16* dA3 = dA0 + 6144;
  u16* dB0 = Bs + tid * 8; u16* dB1 = dB0 + 2048; u16* dB2 = dB0 + 4096; u16* dB3 = dB0 + 6144;
  int lane = tid & 63, wv = tid >> 6;
  int wm = (wv & 1) * 64, wn = (wv >> 1) * 64;
  int lrow = lane & 15, quad = lane >> 4;
  int sl0 = (quad ^ (lrow & 7)) * 8;
  int sl1 = ((quad + 4) ^ (lrow & 7)) * 8;
  f4v zero = {0.f, 0.f, 0.f, 0.f};
  f4v acc[4][4];
#pragma unroll
  for (int i = 0; i < 4; i++)
#pragma unroll
    for (int j = 0; j < 4; j++) acc[i][j] = zero;

  for (int kt = 0; kt < FF / 64; kt++) {
    int ko = kt * 64;
    __syncthreads();
    glds16(gA0 + ko, dA0); glds16(gA1 + ko, dA1);
    glds16(gA2 + ko, dA2); glds16(gA3 + ko, dA3);
    glds16(gB0 + ko, dB0); glds16(gB1 + ko, dB1);
    glds16(gB2 + ko, dB2); glds16(gB3 + ko, dB3);
    __syncthreads();
#pragma unroll
    for (int kk = 0; kk < 2; kk++) {
      int sl = kk ? sl1 : sl0;
      s8v a[4], b[4];
#pragma unroll
      for (int i = 0; i < 4; i++)
        a[i] = *(const s8v*)&As[(wm + i * 16 + lrow) * 64 + sl];
#pragma unroll
      for (int j = 0; j < 4; j++)
        b[j] = *(const s8v*)&Bs[(wn + j * 16 + lrow) * 64 + sl];
#pragma unroll
      for (int i = 0; i < 4; i++)
#pragma unroll
        for (int j = 0; j < 4; j++)
          acc[i][j] = __builtin_amdgcn_mfma_f32_16x16x32_bf16(a[i], b[j], acc[i][j], 0, 0, 0);
    }
  }
#pragma unroll
  for (int i = 0; i < 4; i++) {
#pragma unroll
    for (int r = 0; r < 4; r++) {
      int m = wm + i * 16 + quad * 4 + r;
      if (mt * 128 + m < cnt) {
        int entry = stok[m];       // (t<<1)|k  == ybuf row index
        float w = sw[m];
        long ob = (long)entry * DIM + nt * 128;
#pragma unroll
        for (int j = 0; j < 4; j++)
          ybuf[ob + wn + j * 16 + lrow] = acc[i][j][r] * w;
      }
    }
  }
}

// ---------------- combine + aux ----------------
__global__ __launch_bounds__(256) void combine_aux_kernel(
    const float* __restrict__ ybuf, const int* __restrict__ kflags0,
    const int* __restrict__ kflags1, float* __restrict__ out,
    const int* __restrict__ ctrl) {
  int bid = blockIdx.x;
  if (bid == T_TOK * DIM / 4 / 256) {
    if (threadIdx.x == 0) {
      const float* psum = (const float*)(ctrl + 24);
      const float* zsum = (const float*)(ctrl + 32);
      float lb = 0.f;
      for (int e = 0; e < 8; e++)
        lb += ((float)ctrl[e] / (float)(T_TOK * 2)) * (psum[e] / (float)T_TOK);
      lb *= 8.f;
      float z = zsum[0] / (float)T_TOK;
      out[(size_t)T_TOK * DIM] = 0.01f * lb + 0.001f * z;
    }
    return;
  }
  int idx = bid * 256 + threadIdx.x;   // [0, T*DIM/4)
  int t = idx / (DIM / 4);
  int d4 = idx - t * (DIM / 4);
  float4 r = {0.f, 0.f, 0.f, 0.f};
  if (kflags0[t]) {
    float4 a = ((const float4*)(ybuf + (long)(2 * t) * DIM))[d4];
    r.x += a.x; r.y += a.y; r.z += a.z; r.w += a.w;
  }
  if (kflags1[t]) {
    float4 b = ((const float4*)(ybuf + (long)(2 * t + 1) * DIM))[d4];
    r.x += b.x; r.y += b.y; r.z += b.z; r.w += b.w;
  }
  ((float4*)out)[idx] = r;
}

extern "C" void kernel_launch(void* const* d_in, const int* in_sizes, int n_in,
                              void* d_out, int out_size, void* d_ws, size_t ws_size,
                              hipStream_t stream) {
  const float* x = (const float*)d_in[0];
  const float* wgate = (const float*)d_in[1];
  const float* wig = (const float*)d_in[2];
  const float* wiu = (const float*)d_in[3];
  const float* wo = (const float*)d_in[4];
  float* out = (float*)d_out;

  char* ws = (char*)d_ws;
  size_t off = 0;
  auto alloc = [&](size_t bytes) {
    void* p = ws + off;
    off += (bytes + 255) & ~(size_t)255;
    return p;
  };
  int* ctrl = (int*)alloc(256);
  u16* xb = (u16*)alloc((size_t)T_TOK * DIM * 2);
  u16* wgb = (u16*)alloc((size_t)NE * FF * DIM * 2);
  u16* wub = (u16*)alloc((size_t)NE * FF * DIM * 2);
  u16* wob = (u16*)alloc((size_t)NE * DIM * FF * 2);
  u16* Hbuf = (u16*)alloc((size_t)(T_TOK * 2 + 128) * FF * 2);
  int* tki = (int*)alloc((size_t)T_TOK * 2 * 4);
  float* tkp = (float*)alloc((size_t)T_TOK * 2 * 4);
  int* ltk = (int*)alloc((size_t)NE * LSTR * 4);
  float* lw = (float*)alloc((size_t)NE * LSTR * 4);
  float* probs = (float*)alloc((size_t)T_TOK * 8 * 4);
  float* lse2 = (float*)alloc((size_t)T_TOK * 4);
  int* kflags0 = (int*)alloc((size_t)T_TOK * 4);
  int* kflags1 = (int*)alloc((size_t)T_TOK * 4);
  // ybuf [T*2, DIM] fp32 (50.3MB) aliases wgb+wub (75.5MB): weights dead after gemm1
  float* ybuf = (float*)wgb;

  pre_kernel<<<NCAST2 + T_TOK / 4, 256, 0, stream>>>(
      wig, wiu, wgb, wub, x, wgate, xb, tki, tkp, probs, lse2, ctrl);
  rankred_kernel<<<24, 1024, 0, stream>>>(
      tki, tkp, probs, lse2, ltk, lw, ctrl, kflags0, kflags1);
  gemm1_kernel<<<G1BLK + NWOCAST, 256, 0, stream>>>(
      xb, wgb, wub, Hbuf, ctrl, ltk, wo, wob);
  gemm2_kernel<<<8 * MAXMT * 6, 256, 0, stream>>>(Hbuf, wob, ybuf, ctrl, ltk, lw);
  combine_aux_kernel<<<T_TOK * DIM / 4 / 256 + 1, 256, 0, stream>>>(
      ybuf, kflags0, kflags1, out, ctrl);
}

// Round 10
// 544.418 us; speedup vs baseline: 1.1507x; 1.0030x over previous
//
#include <hip/hip_runtime.h>

typedef unsigned short u16;
typedef unsigned int u32;
typedef unsigned long long u64;

#define T_TOK 8192
#define DIM 768
#define FF 3072
#define NE 8
#define CAP 2560
#define LSTR 5120
#define MAXMT 20
#define N8EACH 2359296          // NE*FF*DIM/8
#define NCAST2 18432            // 2*N8EACH/256 (wig+wiu cast blocks in pre)
#define G1BLK 7680              // 8*48*20 gemm1 tile blocks
#define NWOCAST 2304            // N8EACH/1024 wo-cast blocks appended to gemm1 grid

typedef __attribute__((ext_vector_type(8))) short s8v;
typedef __attribute__((ext_vector_type(4))) float f4v;

__device__ __forceinline__ u16 f2bf(float f) {
  union { float f; u32 u; } v; v.f = f;
  u32 r = v.u + 0x7FFFu + ((v.u >> 16) & 1u);
  return (u16)(r >> 16);
}

__device__ __forceinline__ void glds16(const void* g, void* l) {
  __builtin_amdgcn_global_load_lds(
      (const __attribute__((address_space(1))) u32*)g,
      (__attribute__((address_space(3))) u32*)l, 16, 0, 0);
}

__device__ __forceinline__ void cast8(const float* __restrict__ s, u16* __restrict__ d, int j) {
  const float4* s4 = (const float4*)s;
  float4 a = s4[2 * j], b = s4[2 * j + 1];
  uint4 o;
  o.x = (u32)f2bf(a.x) | ((u32)f2bf(a.y) << 16);
  o.y = (u32)f2bf(a.z) | ((u32)f2bf(a.w) << 16);
  o.z = (u32)f2bf(b.x) | ((u32)f2bf(b.y) << 16);
  o.w = (u32)f2bf(b.z) | ((u32)f2bf(b.w) << 16);
  ((uint4*)d)[j] = o;
}

// ctrl layout (ints): [0..7]=fcnt  [8..15]=cnt0(capped)  [16..23]=cnt1(capped)
//                     [24..31]=psum(float)  [32]=zsum(float)

// ---------------- pre: wig/wiu casts (blocks 0..NCAST2-1) + router (rest); zeroes ctrl ----------------
__global__ __launch_bounds__(256) void pre_kernel(
    const float* __restrict__ wig, const float* __restrict__ wiu,
    u16* __restrict__ wgb, u16* __restrict__ wub,
    const float* __restrict__ x, const float* __restrict__ wg, u16* __restrict__ xb,
    int* __restrict__ tki, float* __restrict__ tkp,
    float* __restrict__ probs, float* __restrict__ lse2, int* __restrict__ ctrl) {
  int bid = blockIdx.x;
  if (bid == 0 && threadIdx.x < 64) ctrl[threadIdx.x] = 0;
  if (bid < NCAST2) {
    int i = bid * 256 + threadIdx.x;
    if (i < N8EACH) cast8(wig, wgb, i);
    else cast8(wiu, wub, i - N8EACH);
    return;
  }
  int rb = bid - NCAST2;
  int lane = threadIdx.x & 63;
  int t = rb * 4 + (threadIdx.x >> 6);
  const float* xr = x + (long)t * DIM;
  u16* xw = xb + (long)t * DIM;
  float acc[NE];
#pragma unroll
  for (int e = 0; e < NE; e++) acc[e] = 0.f;
  for (int i = 0; i < DIM / 64; i++) {
    float xv = xr[lane + 64 * i];
    xw[lane + 64 * i] = f2bf(xv);
#pragma unroll
    for (int e = 0; e < NE; e++) acc[e] += xv * wg[e * DIM + lane + 64 * i];
  }
#pragma unroll
  for (int off = 32; off > 0; off >>= 1) {
#pragma unroll
    for (int e = 0; e < NE; e++) acc[e] += __shfl_xor(acc[e], off);
  }
  if (lane == 0) {
    float m = acc[0];
#pragma unroll
    for (int e = 1; e < NE; e++) m = fmaxf(m, acc[e]);
    float p[NE], s = 0.f;
#pragma unroll
    for (int e = 0; e < NE; e++) { p[e] = __expf(acc[e] - m); s += p[e]; }
    float inv = 1.f / s;
    int e0 = 0;
#pragma unroll
    for (int e = 1; e < NE; e++) if (acc[e] > acc[e0]) e0 = e;
    int e1 = (e0 == 0) ? 1 : 0;
#pragma unroll
    for (int e = 0; e < NE; e++) if (e != e0 && acc[e] > acc[e1]) e1 = e;
    float p0 = p[e0] * inv, p1 = p[e1] * inv;
    float rn = 1.f / (p0 + p1);
    tki[2 * t] = e0; tki[2 * t + 1] = e1;
    tkp[2 * t] = p0 * rn; tkp[2 * t + 1] = p1 * rn;
    float4 pa = {p[0] * inv, p[1] * inv, p[2] * inv, p[3] * inv};
    float4 pb = {p[4] * inv, p[5] * inv, p[6] * inv, p[7] * inv};
    ((float4*)(probs + t * 8))[0] = pa;
    ((float4*)(probs + t * 8))[1] = pb;
    float lse = __logf(s) + m;
    lse2[t] = lse * lse;
  }
}

// ---------------- rankred: blocks 0..15 = per-(e,k) rank; blocks 16..23 = router stats ----------------
__global__ __launch_bounds__(1024) void rankred_kernel(
    const int* __restrict__ tki, const float* __restrict__ tkp,
    const float* __restrict__ probs, const float* __restrict__ lse2,
    int* __restrict__ ltk, float* __restrict__ lw, int* __restrict__ ctrl,
    int* __restrict__ kflags0, int* __restrict__ kflags1) {
  int bid = blockIdx.x;
  int tid = threadIdx.x;
  int wv = tid >> 6, lane = tid & 63;
  if (bid >= 16) {
    // ---- router stats reduce ----
    int t = (bid - 16) * 1024 + tid;
    float4 pa = ((const float4*)(probs + t * 8))[0];
    float4 pb = ((const float4*)(probs + t * 8))[1];
    float p[8] = {pa.x, pa.y, pa.z, pa.w, pb.x, pb.y, pb.z, pb.w};
    float z = lse2[t];
    int e0 = tki[2 * t], e1 = tki[2 * t + 1];
    int fc[8];
#pragma unroll
    for (int e = 0; e < 8; e++) fc[e] = (e0 == e ? 1 : 0) + (e1 == e ? 1 : 0);
#pragma unroll
    for (int off = 32; off > 0; off >>= 1) {
#pragma unroll
      for (int e = 0; e < 8; e++) { p[e] += __shfl_xor(p[e], off); fc[e] += __shfl_xor(fc[e], off); }
      z += __shfl_xor(z, off);
    }
    __shared__ float sp[16][9];
    __shared__ int sf[16][8];
    if (lane == 0) {
#pragma unroll
      for (int e = 0; e < 8; e++) { sp[wv][e] = p[e]; sf[wv][e] = fc[e]; }
      sp[wv][8] = z;
    }
    __syncthreads();
    float* psum = (float*)(ctrl + 24);
    float* zsum = (float*)(ctrl + 32);
    if (tid < 9) {
      float s = 0.f;
      for (int w = 0; w < 16; w++) s += sp[w][tid];
      if (tid < 8) atomicAdd(&psum[tid], s);
      else atomicAdd(zsum, s);
    }
    if (tid >= 64 && tid < 72) {
      int e = tid - 64;
      int s = 0;
      for (int w = 0; w < 16; w++) s += sf[w][e];
      atomicAdd(&ctrl[e], s);
    }
    return;
  }
  // ---- rank block for (e, k): independent prefix-count over token order ----
  int k = bid & 1, e = bid >> 1;
  __shared__ int wcnt[16];
  __shared__ int runbase;
  __shared__ int s_sc0;
  u64 lmask = (lane == 63) ? 0x7FFFFFFFFFFFFFFFull : ((1ull << lane) - 1ull);
  int sc0 = 0;
  if (k == 1) {
    // total top-1 count for e (determines k=1 list base)
    int c0 = 0;
    for (int c = 0; c < T_TOK / 1024; c++) {
      int e0 = tki[2 * (c * 1024 + tid)];
      u64 m = __ballot(e0 == e);
      if (lane == 0) c0 += __popcll(m);
    }
    if (lane == 0) wcnt[wv] = c0;
    __syncthreads();
    if (tid == 0) {
      int s = 0;
      for (int w = 0; w < 16; w++) s += wcnt[w];
      s_sc0 = (s < CAP) ? s : CAP;
    }
    __syncthreads();
    sc0 = s_sc0;
  }
  if (tid == 0) runbase = 0;
  __syncthreads();
  for (int c = 0; c < T_TOK / 1024; c++) {
    int t = c * 1024 + tid;
    int ek = tki[2 * t + k];
    float pk = tkp[2 * t + k];
    u64 m = __ballot(ek == e);
    int pre = __popcll(m & lmask);
    if (lane == 0) wcnt[wv] = __popcll(m);
    __syncthreads();
    int waveoff = runbase;
    for (int w = 0; w < wv; w++) waveoff += wcnt[w];
    int r = waveoff + pre;
    if (ek == e) {
      int keep = (r < CAP) ? 1 : 0;
      if (keep) {
        int p = sc0 + r;
        ltk[e * LSTR + p] = (t << 1) | k;
        lw[e * LSTR + p] = pk;
      }
      if (k == 0) kflags0[t] = keep; else kflags1[t] = keep;
    }
    __syncthreads();
    if (tid == 0) {
      int tot = 0;
      for (int w = 0; w < 16; w++) tot += wcnt[w];
      runbase += tot;
    }
    __syncthreads();
  }
  if (tid == 0) {
    int cnt = runbase; if (cnt > CAP) cnt = CAP;
    ctrl[8 + k * 8 + e] = cnt;
  }
}

// per-block derive of expert count + H-row base from ctrl (cnt0+cnt1, prefix sum)
__device__ __forceinline__ void expert_extent(const int* __restrict__ ctrl, int e,
                                              int& cnt, long& hb0) {
  cnt = 0; hb0 = 0;
#pragma unroll
  for (int i = 0; i < 8; i++) {
    int ci = ctrl[8 + i] + ctrl[16 + i];
    if (i < e) hb0 += ci;
    if (i == e) cnt = ci;
  }
}

// ---------------- GEMM1: tile blocks [0,G1BLK) + wo-cast tail blocks ----------------
__global__ __launch_bounds__(256, 2) void gemm1_kernel(
    const u16* __restrict__ xb, const u16* __restrict__ wgb, const u16* __restrict__ wub,
    u16* __restrict__ H, const int* __restrict__ ctrl, const int* __restrict__ ltk,
    const float* __restrict__ wo, u16* __restrict__ wob) {
  int id = blockIdx.x;
  if (id >= G1BLK) {
    // wo cast riding in gemm1's shadow (gemm1 is latency-bound, HBM at ~22%)
    int base = (id - G1BLK) * 1024 + threadIdx.x;
#pragma unroll
    for (int c = 0; c < 4; c++) cast8(wo, wob, base + c * 256);
    return;
  }
  // swizzle: groups g=(e*48+nt) share weights; members mt on same XCD
  int xcd = id & 7;
  int q = id >> 3;          // [0, 960)
  int gg = q / MAXMT;       // [0, 48)
  int mt = q - gg * MAXMT;  // [0, 20)
  int g = gg * 8 + xcd;     // [0, 384)
  int e = g / 48;
  int nt = g - e * 48;      // [0, 48)
  int cnt; long hb0;
  expert_extent(ctrl, e, cnt, hb0);
  if (mt * 128 >= cnt) return;

  __shared__ u16 As[128 * 64];
  __shared__ u16 Bg[64 * 64];
  __shared__ u16 Bu[64 * 64];
  __shared__ int toks[128];
  int tid = threadIdx.x;
  if (tid < 128) {
    int r = mt * 128 + tid; if (r > cnt - 1) r = cnt - 1;
    toks[tid] = ltk[e * LSTR + r] >> 1;
  }
  __syncthreads();
  int rq8 = tid >> 3;                     // [0,32)
  int swz = ((tid & 7) ^ (rq8 & 7)) * 8;  // swizzled 8xu16 chunk within 64-col row
  long tA0 = toks[rq8], tA1 = toks[32 + rq8], tA2 = toks[64 + rq8], tA3 = toks[96 + rq8];
  const u16* gA0 = xb + tA0 * DIM + swz;
  const u16* gA1 = xb + tA1 * DIM + swz;
  const u16* gA2 = xb + tA2 * DIM + swz;
  const u16* gA3 = xb + tA3 * DIM + swz;
  long bO0 = ((long)e * FF + nt * 64 + rq8) * DIM + swz;
  long bO1 = bO0 + 32l * DIM;
  const u16* gG0 = wgb + bO0; const u16* gG1 = wgb + bO1;
  const u16* gU0 = wub + bO0; const u16* gU1 = wub + bO1;
  u16* dA0 = As + tid * 8; u16* dA1 = dA0 + 2048; u16* dA2 = dA0 + 4096; u16* dA3 = dA0 + 6144;
  u16* dG0 = Bg + tid * 8; u16* dG1 = dG0 + 2048;
  u16* dU0 = Bu + tid * 8; u16* dU1 = dU0 + 2048;

  int lane = tid & 63, wv = tid >> 6;
  int wm = (wv & 1) * 64, wn = (wv >> 1) * 32;
  int lrow = lane & 15, quad = lane >> 4;
  int sl0 = (quad ^ (lrow & 7)) * 8;
  int sl1 = ((quad + 4) ^ (lrow & 7)) * 8;

  f4v zero = {0.f, 0.f, 0.f, 0.f};
  f4v accg[4][2], accu[4][2];
#pragma unroll
  for (int i = 0; i < 4; i++)
#pragma unroll
    for (int j = 0; j < 2; j++) { accg[i][j] = zero; accu[i][j] = zero; }

  for (int kt = 0; kt < DIM / 64; kt++) {
    int ko = kt * 64;
    __syncthreads();
    glds16(gA0 + ko, dA0); glds16(gA1 + ko, dA1);
    glds16(gA2 + ko, dA2); glds16(gA3 + ko, dA3);
    glds16(gG0 + ko, dG0); glds16(gG1 + ko, dG1);
    glds16(gU0 + ko, dU0); glds16(gU1 + ko, dU1);
    __syncthreads();
#pragma unroll
    for (int kk = 0; kk < 2; kk++) {
      int sl = kk ? sl1 : sl0;
      s8v a[4], bgf[2], buf[2];
#pragma unroll
      for (int i = 0; i < 4; i++)
        a[i] = *(const s8v*)&As[(wm + i * 16 + lrow) * 64 + sl];
#pragma unroll
      for (int j = 0; j < 2; j++) {
        bgf[j] = *(const s8v*)&Bg[(wn + j * 16 + lrow) * 64 + sl];
        buf[j] = *(const s8v*)&Bu[(wn + j * 16 + lrow) * 64 + sl];
      }
#pragma unroll
      for (int i = 0; i < 4; i++)
#pragma unroll
        for (int j = 0; j < 2; j++) {
          accg[i][j] = __builtin_amdgcn_mfma_f32_16x16x32_bf16(a[i], bgf[j], accg[i][j], 0, 0, 0);
          accu[i][j] = __builtin_amdgcn_mfma_f32_16x16x32_bf16(a[i], buf[j], accu[i][j], 0, 0, 0);
        }
    }
  }
  long hb = hb0 + (long)mt * 128;
#pragma unroll
  for (int i = 0; i < 4; i++) {
#pragma unroll
    for (int r = 0; r < 4; r++) {
      int m = wm + i * 16 + quad * 4 + r;
      if (mt * 128 + m < cnt) {
#pragma unroll
        for (int j = 0; j < 2; j++) {
          float gv = accg[i][j][r], uv = accu[i][j][r];
          float h = gv / (1.f + __expf(-gv)) * uv;
          H[(hb + m) * FF + nt * 64 + wn + j * 16 + lrow] = f2bf(h);
        }
      }
    }
  }
}

// ---------------- GEMM2: tile 256x128, 512 threads; ybuf[(t,k)] = (H @ wo^T) * w ----------------
// wob tile re-read halves vs 128-tile (10 mt instead of 20); 480 blocks all co-resident.
__global__ __launch_bounds__(512, 2) void gemm2_kernel(
    const u16* __restrict__ H, const u16* __restrict__ wob,
    float* __restrict__ ybuf, const int* __restrict__ ctrl,
    const int* __restrict__ ltk, const float* __restrict__ lw) {
  // groups g=(e*10+mt) share H rows; members nt on same XCD
  int id = blockIdx.x;
  int xcd = id & 7;
  int q = id >> 3;        // [0, 60)
  int gg = q / 6;         // [0, 10)
  int nt = q - gg * 6;    // [0, 6)
  int g = gg * 8 + xcd;   // [0, 80)
  int e = g / 10;
  int mt = g - e * 10;
  int cnt; long hb0;
  expert_extent(ctrl, e, cnt, hb0);
  if (mt * 256 >= cnt) return;

  __shared__ u16 As[256 * 64];
  __shared__ u16 Bs[128 * 64];
  __shared__ int stok[256];
  __shared__ float sw[256];
  int tid = threadIdx.x;
  if (tid < 256) {
    int r = mt * 256 + tid; if (r > cnt - 1) r = cnt - 1;
    stok[tid] = ltk[e * LSTR + r];
    sw[tid] = lw[e * LSTR + r];
  }
  long hb = hb0 + (long)mt * 256;
  int rq8 = tid >> 3;                     // [0,64)
  int swz = ((tid & 7) ^ (rq8 & 7)) * 8;  // chunk stride 512 threads = 64 rows; row&7 invariant
  const u16* gA0 = H + (hb + rq8) * FF + swz;
  const u16* gA1 = gA0 + 64l * FF;
  const u16* gA2 = gA0 + 128l * FF;
  const u16* gA3 = gA0 + 192l * FF;
  long bOff = ((long)e * DIM + nt * 128 + rq8) * FF + swz;
  const u16* gB0 = wob + bOff;
  const u16* gB1 = gB0 + 64l * FF;
  u16* dA0 = As + tid * 8; u16* dA1 = dA0 + 4096; u16* dA2 = dA0 + 8192; u16* dA3 = dA0 + 12288;
  u16* dB0 = Bs + tid * 8; u16* dB1 = dB0 + 4096;
  int lane = tid & 63, wv = tid >> 6;     // wv in [0,8)
  int wm = (wv & 3) * 64, wn = (wv >> 2) * 64;
  int lrow = lane & 15, quad = lane >> 4;
  int sl0 = (quad ^ (lrow & 7)) * 8;
  int sl1 = ((quad + 4) ^ (lrow & 7)) * 8;
  f4v zero = {0.f, 0.f, 0.f, 0.f};
  f4v acc[4][4];
#pragma unroll
  for (int i = 0; i < 4; i++)
#pragma unroll
    for (int j = 0; j < 4; j++) acc[i][j] = zero;

  for (int kt = 0; kt < FF / 64; kt++) {
    int ko = kt * 64;
    __syncthreads();
    glds16(gA0 + ko, dA0); glds16(gA1 + ko, dA1);
    glds16(gA2 + ko, dA2); glds16(gA3 + ko, dA3);
    glds16(gB0 + ko, dB0); glds16(gB1 + ko, dB1);
    __syncthreads();
#pragma unroll
    for (int kk = 0; kk < 2; kk++) {
      int sl = kk ? sl1 : sl0;
      s8v a[4], b[4];
#pragma unroll
      for (int i = 0; i < 4; i++)
        a[i] = *(const s8v*)&As[(wm + i * 16 + lrow) * 64 + sl];
#pragma unroll
      for (int j = 0; j < 4; j++)
        b[j] = *(const s8v*)&Bs[(wn + j * 16 + lrow) * 64 + sl];
#pragma unroll
      for (int i = 0; i < 4; i++)
#pragma unroll
        for (int j = 0; j < 4; j++)
          acc[i][j] = __builtin_amdgcn_mfma_f32_16x16x32_bf16(a[i], b[j], acc[i][j], 0, 0, 0);
    }
  }
#pragma unroll
  for (int i = 0; i < 4; i++) {
#pragma unroll
    for (int r = 0; r < 4; r++) {
      int m = wm + i * 16 + quad * 4 + r;
      if (mt * 256 + m < cnt) {
        int entry = stok[m];       // (t<<1)|k  == ybuf row index
        float w = sw[m];
        long ob = (long)entry * DIM + nt * 128;
#pragma unroll
        for (int j = 0; j < 4; j++)
          ybuf[ob + wn + j * 16 + lrow] = acc[i][j][r] * w;
      }
    }
  }
}

// ---------------- combine + aux ----------------
__global__ __launch_bounds__(256) void combine_aux_kernel(
    const float* __restrict__ ybuf, const int* __restrict__ kflags0,
    const int* __restrict__ kflags1, float* __restrict__ out,
    const int* __restrict__ ctrl) {
  int bid = blockIdx.x;
  if (bid == T_TOK * DIM / 4 / 256) {
    if (threadIdx.x == 0) {
      const float* psum = (const float*)(ctrl + 24);
      const float* zsum = (const float*)(ctrl + 32);
      float lb = 0.f;
      for (int e = 0; e < 8; e++)
        lb += ((float)ctrl[e] / (float)(T_TOK * 2)) * (psum[e] / (float)T_TOK);
      lb *= 8.f;
      float z = zsum[0] / (float)T_TOK;
      out[(size_t)T_TOK * DIM] = 0.01f * lb + 0.001f * z;
    }
    return;
  }
  int idx = bid * 256 + threadIdx.x;   // [0, T*DIM/4)
  int t = idx / (DIM / 4);
  int d4 = idx - t * (DIM / 4);
  float4 r = {0.f, 0.f, 0.f, 0.f};
  if (kflags0[t]) {
    float4 a = ((const float4*)(ybuf + (long)(2 * t) * DIM))[d4];
    r.x += a.x; r.y += a.y; r.z += a.z; r.w += a.w;
  }
  if (kflags1[t]) {
    float4 b = ((const float4*)(ybuf + (long)(2 * t + 1) * DIM))[d4];
    r.x += b.x; r.y += b.y; r.z += b.z; r.w += b.w;
  }
  ((float4*)out)[idx] = r;
}

extern "C" void kernel_launch(void* const* d_in, const int* in_sizes, int n_in,
                              void* d_out, int out_size, void* d_ws, size_t ws_size,
                              hipStream_t stream) {
  const float* x = (const float*)d_in[0];
  const float* wgate = (const float*)d_in[1];
  const float* wig = (const float*)d_in[2];
  const float* wiu = (const float*)d_in[3];
  const float* wo = (const float*)d_in[4];
  float* out = (float*)d_out;

  char* ws = (char*)d_ws;
  size_t off = 0;
  auto alloc = [&](size_t bytes) {
    void* p = ws + off;
    off += (bytes + 255) & ~(size_t)255;
    return p;
  };
  int* ctrl = (int*)alloc(256);
  u16* xb = (u16*)alloc((size_t)T_TOK * DIM * 2);
  u16* wgb = (u16*)alloc((size_t)NE * FF * DIM * 2);
  u16* wub = (u16*)alloc((size_t)NE * FF * DIM * 2);
  u16* wob = (u16*)alloc((size_t)NE * DIM * FF * 2);
  u16* Hbuf = (u16*)alloc((size_t)(T_TOK * 2 + 256) * FF * 2);  // +256 pad for 256-row A tiles
  int* tki = (int*)alloc((size_t)T_TOK * 2 * 4);
  float* tkp = (float*)alloc((size_t)T_TOK * 2 * 4);
  int* ltk = (int*)alloc((size_t)NE * LSTR * 4);
  float* lw = (float*)alloc((size_t)NE * LSTR * 4);
  float* probs = (float*)alloc((size_t)T_TOK * 8 * 4);
  float* lse2 = (float*)alloc((size_t)T_TOK * 4);
  int* kflags0 = (int*)alloc((size_t)T_TOK * 4);
  int* kflags1 = (int*)alloc((size_t)T_TOK * 4);
  // ybuf [T*2, DIM] fp32 (50.3MB) aliases wgb+wub (75.5MB): weights dead after gemm1
  float* ybuf = (float*)wgb;

  pre_kernel<<<NCAST2 + T_TOK / 4, 256, 0, stream>>>(
      wig, wiu, wgb, wub, x, wgate, xb, tki, tkp, probs, lse2, ctrl);
  rankred_kernel<<<24, 1024, 0, stream>>>(
      tki, tkp, probs, lse2, ltk, lw, ctrl, kflags0, kflags1);
  gemm1_kernel<<<G1BLK + NWOCAST, 256, 0, stream>>>(
      xb, wgb, wub, Hbuf, ctrl, ltk, wo, wob);
  gemm2_kernel<<<480, 512, 0, stream>>>(Hbuf, wob, ybuf, ctrl, ltk, lw);
  combine_aux_kernel<<<T_TOK * DIM / 4 / 256 + 1, 256, 0, stream>>>(
      ybuf, kflags0, kflags1, out, ctrl);
}